// Round 3
// baseline (813.287 us; speedup 1.0000x reference)
//
#include <hip/hip_runtime.h>
#include <hip/hip_bf16.h>

// Problem dims
#define Bd 16
#define Cd 3
#define Hd 64
#define Wd 64
#define Pd 256
#define PSd 9
#define Ed 256
#define NHd 8
#define DHd 32
#define HWd 4096
#define POSDd 64

// ---------------------------------------------------------------------------
// K0a: G[e][j] = sum_hw out_w[e,hw] * fc_w[hw,j]   (e<256, j<2)
//      blocks 256,257: h0[j] = sum_hw out_b[hw]*fc_w[hw,j] + fc_b[j]
// ---------------------------------------------------------------------------
__global__ __launch_bounds__(64) void precompute_G(
    const float* __restrict__ out_w, const float* __restrict__ fc_w,
    const float* __restrict__ out_b, const float* __restrict__ fc_b,
    float* __restrict__ G, float* __restrict__ h0) {
    int blk = blockIdx.x, lane = threadIdx.x;
    if (blk < 256) {
        int e = blk;
        float a0 = 0.f, a1 = 0.f;
        for (int i = lane; i < HWd; i += 64) {
            float a = out_w[e * HWd + i];
            a0 += a * fc_w[2 * i];
            a1 += a * fc_w[2 * i + 1];
        }
        #pragma unroll
        for (int off = 32; off; off >>= 1) { a0 += __shfl_xor(a0, off); a1 += __shfl_xor(a1, off); }
        if (lane == 0) { G[2 * e] = a0; G[2 * e + 1] = a1; }
    } else {
        int j = blk - 256;
        float a = 0.f;
        for (int i = lane; i < HWd; i += 64) a += out_b[i] * fc_w[2 * i + j];
        #pragma unroll
        for (int off = 32; off; off >>= 1) a += __shfl_xor(a, off);
        if (lane == 0) h0[j] = a + fc_b[j];
    }
}

// ---------------------------------------------------------------------------
// K0b: M2[e][j] = sum_f wo[e,f] * G[f][j];  h0[j] += sum_e bo[e]*G[e][j]
// ---------------------------------------------------------------------------
__global__ __launch_bounds__(256) void precompute_M2(
    const float* __restrict__ wo, const float* __restrict__ bo,
    const float* __restrict__ G, float* __restrict__ M2, float* __restrict__ h0) {
    int e = threadIdx.x;
    float m0 = 0.f, m1 = 0.f;
    for (int f = 0; f < Ed; f++) {
        float wv = wo[e * Ed + f];
        m0 += wv * G[2 * f];
        m1 += wv * G[2 * f + 1];
    }
    M2[2 * e] = m0;
    M2[2 * e + 1] = m1;
    if (e < 2) {
        float hh = 0.f;
        for (int f = 0; f < Ed; f++) hh += bo[f] * G[2 * f + e];
        h0[e] += hh;
    }
}

// ---------------------------------------------------------------------------
// K1: conv 9x9 pad4 + bias + relu.  feat[bp_local,hw] fp32 (chunked over b).
// One block per (b_local,p); x[b] zero-padded in LDS; 16 consecutive px/thread.
// ---------------------------------------------------------------------------
__global__ __launch_bounds__(256) void conv_relu(
    const float* __restrict__ x, const float* __restrict__ conv_w,
    const float* __restrict__ conv_b, float* __restrict__ feat) {
    __shared__ float xpad[3][72][72];
    __shared__ float wsh[243];
    int blk = blockIdx.x;
    int b = blk >> 8, p = blk & 255;
    int tid = threadIdx.x;

    float* xf = &xpad[0][0][0];
    for (int i = tid; i < 3 * 72 * 72; i += 256) xf[i] = 0.f;
    __syncthreads();
    const float* xb = x + b * 3 * HWd;
    for (int i = tid; i < 3 * HWd; i += 256) {
        int c = i >> 12, rem = i & 4095, y = rem >> 6, xx = rem & 63;
        xpad[c][y + 4][xx + 4] = xb[i];
    }
    if (tid < 243) wsh[tid] = conv_w[p * 243 + tid];
    __syncthreads();

    float bias = conv_b[p];
    int y = tid >> 2, x0 = (tid & 3) << 4;
    float acc[16];
    #pragma unroll
    for (int i = 0; i < 16; i++) acc[i] = bias;

    for (int c = 0; c < 3; c++) {
        #pragma unroll 1
        for (int dy = 0; dy < 9; dy++) {
            float r[24];
            #pragma unroll
            for (int t = 0; t < 24; t++) r[t] = xpad[c][y + dy][x0 + t];
            #pragma unroll
            for (int dx = 0; dx < 9; dx++) {
                float wv = wsh[c * 81 + dy * 9 + dx];
                #pragma unroll
                for (int i = 0; i < 16; i++) acc[i] = fmaf(r[i + dx], wv, acc[i]);
            }
        }
    }
    float* outp = feat + (size_t)blk * HWd + y * Wd + x0;
    #pragma unroll
    for (int i = 0; i < 16; i++) outp[i] = fmaxf(acc[i], 0.f);
}

// ---------------------------------------------------------------------------
// K2: fp32 tiled GEMM, C = A@B + bias.  64x64 tile, BK=16.
// ---------------------------------------------------------------------------
__global__ __launch_bounds__(256) void gemm_f32(
    const float* __restrict__ A, const float* __restrict__ Bw,
    const float* __restrict__ bias, float* __restrict__ C,
    int M, int N, int K) {
    __shared__ float As[16][65];
    __shared__ float Bs[16][65];
    int tid = threadIdx.x;
    int nb = blockIdx.x * 64, mb = blockIdx.y * 64;
    int tx = tid & 15, ty = tid >> 4;
    int am = tid >> 2, ak = (tid & 3) << 2;
    int bk = tid >> 4, bn = (tid & 15) << 2;
    float acc[4][4];
    #pragma unroll
    for (int i = 0; i < 4; i++)
        #pragma unroll
        for (int j = 0; j < 4; j++) acc[i][j] = 0.f;

    for (int k0 = 0; k0 < K; k0 += 16) {
        float4 a4 = *(const float4*)(A + (size_t)(mb + am) * K + k0 + ak);
        As[ak + 0][am] = a4.x; As[ak + 1][am] = a4.y;
        As[ak + 2][am] = a4.z; As[ak + 3][am] = a4.w;
        float4 b4 = *(const float4*)(Bw + (size_t)(k0 + bk) * N + nb + bn);
        Bs[bk][bn + 0] = b4.x; Bs[bk][bn + 1] = b4.y;
        Bs[bk][bn + 2] = b4.z; Bs[bk][bn + 3] = b4.w;
        __syncthreads();
        #pragma unroll
        for (int k = 0; k < 16; k++) {
            float a0 = As[k][ty * 4 + 0], a1 = As[k][ty * 4 + 1];
            float a2 = As[k][ty * 4 + 2], a3 = As[k][ty * 4 + 3];
            float b0 = Bs[k][tx * 4 + 0], b1 = Bs[k][tx * 4 + 1];
            float b2 = Bs[k][tx * 4 + 2], b3 = Bs[k][tx * 4 + 3];
            acc[0][0] = fmaf(a0, b0, acc[0][0]); acc[0][1] = fmaf(a0, b1, acc[0][1]);
            acc[0][2] = fmaf(a0, b2, acc[0][2]); acc[0][3] = fmaf(a0, b3, acc[0][3]);
            acc[1][0] = fmaf(a1, b0, acc[1][0]); acc[1][1] = fmaf(a1, b1, acc[1][1]);
            acc[1][2] = fmaf(a1, b2, acc[1][2]); acc[1][3] = fmaf(a1, b3, acc[1][3]);
            acc[2][0] = fmaf(a2, b0, acc[2][0]); acc[2][1] = fmaf(a2, b1, acc[2][1]);
            acc[2][2] = fmaf(a2, b2, acc[2][2]); acc[2][3] = fmaf(a2, b3, acc[2][3]);
            acc[3][0] = fmaf(a3, b0, acc[3][0]); acc[3][1] = fmaf(a3, b1, acc[3][1]);
            acc[3][2] = fmaf(a3, b2, acc[3][2]); acc[3][3] = fmaf(a3, b3, acc[3][3]);
        }
        __syncthreads();
    }
    #pragma unroll
    for (int i = 0; i < 4; i++) {
        #pragma unroll
        for (int j = 0; j < 4; j++) {
            int n = nb + tx * 4 + j;
            C[(size_t)(mb + ty * 4 + i) * N + n] = acc[i][j] + bias[n];
        }
    }
}

// ---------------------------------------------------------------------------
// K4: attention. One block per (b,h); thread r = q-row. Online softmax.
// ---------------------------------------------------------------------------
__global__ __launch_bounds__(256) void attention(
    const float* __restrict__ q, const float* __restrict__ k,
    const float* __restrict__ v, float* __restrict__ o) {
    __shared__ float ksh[128][32];
    __shared__ float vsh[128][32];
    int blk = blockIdx.x;          // b*8 + h
    int b = blk >> 3, h = blk & 7;
    int r = threadIdx.x;
    const float rs = 0.17677669529663687f;  // 1/sqrt(32)

    float qr[32];
    const float* qrow = q + ((size_t)(b * Pd + r)) * Ed + h * DHd;
    #pragma unroll
    for (int d = 0; d < 32; d++) qr[d] = qrow[d];

    float m = -1e30f, l = 0.f;
    float oacc[32];
    #pragma unroll
    for (int d = 0; d < 32; d++) oacc[d] = 0.f;

    for (int ch = 0; ch < 2; ch++) {
        __syncthreads();
        {
            int row = r >> 1, dh = (r & 1) << 4;
            const float* srck = k + ((size_t)(b * Pd + ch * 128 + row)) * Ed + h * DHd + dh;
            const float* srcv = v + ((size_t)(b * Pd + ch * 128 + row)) * Ed + h * DHd + dh;
            #pragma unroll
            for (int i = 0; i < 16; i++) { ksh[row][dh + i] = srck[i]; vsh[row][dh + i] = srcv[i]; }
        }
        __syncthreads();
        for (int kk = 0; kk < 128; kk++) {
            float s = 0.f;
            #pragma unroll
            for (int d = 0; d < 32; d++) s = fmaf(qr[d], ksh[kk][d], s);
            s *= rs;
            float mnew = fmaxf(m, s);
            float scale = __expf(m - mnew);
            float pexp = __expf(s - mnew);
            l = l * scale + pexp;
            #pragma unroll
            for (int d = 0; d < 32; d++) oacc[d] = fmaf(oacc[d], scale, pexp * vsh[kk][d]);
            m = mnew;
        }
    }
    float rinv = 1.f / l;
    float* orow = o + ((size_t)(b * Pd + r)) * Ed + h * DHd;
    #pragma unroll
    for (int d = 0; d < 32; d++) orow[d] = oacc[d] * rinv;
}

// ---------------------------------------------------------------------------
// K5: fused head. One wave per (b,p): tp = tanh(o@M2 + h0); pos embed; patches.
// ---------------------------------------------------------------------------
#define PATCH_OUT 995328   // 16*256*243
__global__ __launch_bounds__(256) void head_kernel(
    const float* __restrict__ o, const float* __restrict__ M2,
    const float* __restrict__ h0, const float* __restrict__ pos_w,
    const float* __restrict__ pos_b, const float* __restrict__ x,
    float* __restrict__ out) {
    int w = threadIdx.x >> 6, lane = threadIdx.x & 63;
    int bp = blockIdx.x * 4 + w;
    int b = bp >> 8;

    const float* orow = o + (size_t)bp * Ed;
    float4 o4 = *(const float4*)(orow + lane * 4);
    int e0 = lane * 4;
    float s0 = o4.x * M2[2 * e0 + 0] + o4.y * M2[2 * e0 + 2] + o4.z * M2[2 * e0 + 4] + o4.w * M2[2 * e0 + 6];
    float s1 = o4.x * M2[2 * e0 + 1] + o4.y * M2[2 * e0 + 3] + o4.z * M2[2 * e0 + 5] + o4.w * M2[2 * e0 + 7];
    #pragma unroll
    for (int off = 32; off; off >>= 1) { s0 += __shfl_xor(s0, off); s1 += __shfl_xor(s1, off); }

    float tx = tanhf(s0 + h0[0]);
    float ty = tanhf(s1 + h0[1]);

    // pos embed: lane = output dim d (POSD==64)
    {
        float pv = tx * pos_w[lane] + ty * pos_w[64 + lane] + pos_b[lane];
        out[PATCH_OUT + bp * POSDd + lane] = pv;
    }

    // patches: 243 bilinear samples, 4 per lane
    const float* xb = x + b * 3 * HWd;
    #pragma unroll
    for (int s = 0; s < 4; s++) {
        int idx = s * 64 + lane;
        if (idx < 243) {
            int c = idx / 81;
            int rem = idx - c * 81;
            int iy = rem / 9;
            int jx = rem - iy * 9;
            float basex = (2.f * jx + 1.f) / 9.f - 1.f;
            float basey = (2.f * iy + 1.f) / 9.f - 1.f;
            float gx = 0.140625f * basex + tx;   // PS/W = 9/64 exact
            float gy = 0.140625f * basey + ty;
            float ix  = ((gx + 1.f) * 64.f - 1.f) * 0.5f;
            float iyf = ((gy + 1.f) * 64.f - 1.f) * 0.5f;
            float x0f = floorf(ix), y0f = floorf(iyf);
            float wx = ix - x0f, wy = iyf - y0f;
            int x0i = min(max((int)x0f, 0), 63);
            int x1i = min(max((int)x0f + 1, 0), 63);
            int y0i = min(max((int)y0f, 0), 63);
            int y1i = min(max((int)y0f + 1, 0), 63);
            const float* xc = xb + c * HWd;
            float v00 = xc[y0i * Wd + x0i];
            float v01 = xc[y0i * Wd + x1i];
            float v10 = xc[y1i * Wd + x0i];
            float v11 = xc[y1i * Wd + x1i];
            float val = v00 * (1.f - wx) * (1.f - wy) + v01 * wx * (1.f - wy)
                      + v10 * (1.f - wx) * wy + v11 * wx * wy;
            out[bp * 243 + idx] = val;
        }
    }
}

// ---------------------------------------------------------------------------
extern "C" void kernel_launch(void* const* d_in, const int* in_sizes, int n_in,
                              void* d_out, int out_size, void* d_ws, size_t ws_size,
                              hipStream_t stream) {
    (void)in_sizes; (void)n_in; (void)out_size;
    const float* x      = (const float*)d_in[0];
    const float* conv_w = (const float*)d_in[1];
    const float* conv_b = (const float*)d_in[2];
    const float* in_w   = (const float*)d_in[3];
    const float* in_b   = (const float*)d_in[4];
    const float* wq     = (const float*)d_in[5];
    const float* bq     = (const float*)d_in[6];
    const float* wk     = (const float*)d_in[7];
    const float* bk     = (const float*)d_in[8];
    const float* wv     = (const float*)d_in[9];
    const float* bv     = (const float*)d_in[10];
    const float* wo     = (const float*)d_in[11];
    const float* bo     = (const float*)d_in[12];
    const float* out_w  = (const float*)d_in[13];
    const float* out_b  = (const float*)d_in[14];
    const float* fc_w   = (const float*)d_in[15];
    const float* fc_b   = (const float*)d_in[16];
    const float* pos_w  = (const float*)d_in[17];
    const float* pos_b  = (const float*)d_in[18];

    // Batch-chunked feat to fit ws_size: feat = CB*4MB, rest = ~20.98 MB.
    const size_t rest_f = 5ull * 1048576 + 1026;           // floats after feat
    int CB = 16;
    while (CB > 1 && ((size_t)CB * 1048576 + rest_f) * 4 > ws_size) CB >>= 1;
    int nchunks = 16 / CB;

    float* ws   = (float*)d_ws;
    float* feat = ws;                                      // CB*1M floats
    float* tok  = feat + (size_t)CB * 1048576;             // 1M
    float* q    = tok + 1048576;
    float* k    = q + 1048576;
    float* v    = k + 1048576;
    float* o    = v + 1048576;
    float* G    = o + 1048576;                             // 512
    float* M2   = G + 512;                                 // 512
    float* h0   = M2 + 512;                                // 2
    float* out  = (float*)d_out;

    hipLaunchKernelGGL(precompute_G, dim3(258), dim3(64), 0, stream,
                       out_w, fc_w, out_b, fc_b, G, h0);
    hipLaunchKernelGGL(precompute_M2, dim3(1), dim3(256), 0, stream,
                       wo, bo, G, M2, h0);
    for (int c = 0; c < nchunks; ++c) {
        hipLaunchKernelGGL(conv_relu, dim3(CB * 256), dim3(256), 0, stream,
                           x + (size_t)c * CB * 3 * HWd, conv_w, conv_b, feat);
        hipLaunchKernelGGL(gemm_f32, dim3(4, CB * 4), dim3(256), 0, stream,
                           feat, in_w, in_b, tok + (size_t)c * CB * 256 * 256,
                           CB * 256, 256, 4096);
    }
    hipLaunchKernelGGL(gemm_f32, dim3(4, 64), dim3(256), 0, stream,
                       tok, wq, bq, q, 4096, 256, 256);
    hipLaunchKernelGGL(gemm_f32, dim3(4, 64), dim3(256), 0, stream,
                       tok, wk, bk, k, 4096, 256, 256);
    hipLaunchKernelGGL(gemm_f32, dim3(4, 64), dim3(256), 0, stream,
                       tok, wv, bv, v, 4096, 256, 256);
    hipLaunchKernelGGL(attention, dim3(128), dim3(256), 0, stream, q, k, v, o);
    hipLaunchKernelGGL(head_kernel, dim3(1024), dim3(256), 0, stream,
                       o, M2, h0, pos_w, pos_b, x, out);
}

// Round 4
// 584.077 us; speedup vs baseline: 1.3924x; 1.3924x over previous
//
#include <hip/hip_runtime.h>
#include <hip/hip_bf16.h>

// Problem dims
#define Bd 16
#define Cd 3
#define Hd 64
#define Wd 64
#define Pd 256
#define PSd 9
#define Ed 256
#define NHd 8
#define DHd 32
#define HWd 4096
#define POSDd 64

typedef unsigned short u16;
typedef short short8 __attribute__((ext_vector_type(8)));
typedef float f32x4 __attribute__((ext_vector_type(4)));

__device__ __forceinline__ float bf2f(u16 u) {
    union { unsigned int i; float f; } c; c.i = ((unsigned int)u) << 16; return c.f;
}
__device__ __forceinline__ u16 f2bf(float f) {
    unsigned int x = __float_as_uint(f);
    unsigned int r = (x + 0x7fffu + ((x >> 16) & 1u)) >> 16;
    return (u16)r;
}

// ---------------------------------------------------------------------------
// K0a: G[e][j] = sum_hw out_w[e,hw] * fc_w[hw,j]   (e<256, j<2)
//      blocks 256,257: h0[j] = sum_hw out_b[hw]*fc_w[hw,j] + fc_b[j]
// ---------------------------------------------------------------------------
__global__ __launch_bounds__(64) void precompute_G(
    const float* __restrict__ out_w, const float* __restrict__ fc_w,
    const float* __restrict__ out_b, const float* __restrict__ fc_b,
    float* __restrict__ G, float* __restrict__ h0) {
    int blk = blockIdx.x, lane = threadIdx.x;
    if (blk < 256) {
        int e = blk;
        float a0 = 0.f, a1 = 0.f;
        for (int i = lane; i < HWd; i += 64) {
            float a = out_w[e * HWd + i];
            a0 += a * fc_w[2 * i];
            a1 += a * fc_w[2 * i + 1];
        }
        #pragma unroll
        for (int off = 32; off; off >>= 1) { a0 += __shfl_xor(a0, off); a1 += __shfl_xor(a1, off); }
        if (lane == 0) { G[2 * e] = a0; G[2 * e + 1] = a1; }
    } else {
        int j = blk - 256;
        float a = 0.f;
        for (int i = lane; i < HWd; i += 64) a += out_b[i] * fc_w[2 * i + j];
        #pragma unroll
        for (int off = 32; off; off >>= 1) a += __shfl_xor(a, off);
        if (lane == 0) h0[j] = a + fc_b[j];
    }
}

// ---------------------------------------------------------------------------
// K0b: M2[e][j] = sum_f wo[e,f] * G[f][j];  h0[j] += sum_e bo[e]*G[e][j]
// ---------------------------------------------------------------------------
__global__ __launch_bounds__(256) void precompute_M2(
    const float* __restrict__ wo, const float* __restrict__ bo,
    const float* __restrict__ G, float* __restrict__ M2, float* __restrict__ h0) {
    int e = threadIdx.x;
    float m0 = 0.f, m1 = 0.f;
    for (int f = 0; f < Ed; f++) {
        float wv = wo[e * Ed + f];
        m0 += wv * G[2 * f];
        m1 += wv * G[2 * f + 1];
    }
    M2[2 * e] = m0;
    M2[2 * e + 1] = m1;
    if (e < 2) {
        float hh = 0.f;
        for (int f = 0; f < Ed; f++) hh += bo[f] * G[2 * f + e];
        h0[e] += hh;
    }
}

// ---------------------------------------------------------------------------
// prep: W[K][256] fp32 -> Wt_hi/Wt_lo[256][K] bf16 (transposed + hi/lo split)
// grid = K blocks of 256 threads.
// ---------------------------------------------------------------------------
__global__ __launch_bounds__(256) void prep_weight(
    const float* __restrict__ W, u16* __restrict__ Th, u16* __restrict__ Tl,
    int K) {
    int idx = blockIdx.x * 256 + threadIdx.x;   // = k*256 + n
    int k = idx >> 8, n = idx & 255;
    float v = W[idx];
    u16 h = f2bf(v);
    Th[(size_t)n * K + k] = h;
    Tl[(size_t)n * K + k] = f2bf(v - bf2f(h));
}

// ---------------------------------------------------------------------------
// K1: conv 9x9 pad4 + bias + relu -> feat as bf16 hi/lo pair [bp][hw].
// ---------------------------------------------------------------------------
__global__ __launch_bounds__(256) void conv_relu(
    const float* __restrict__ x, const float* __restrict__ conv_w,
    const float* __restrict__ conv_b,
    u16* __restrict__ feat_hi, u16* __restrict__ feat_lo) {
    __shared__ float xpad[3][72][72];
    __shared__ float wsh[243];
    int blk = blockIdx.x;
    int b = blk >> 8, p = blk & 255;
    int tid = threadIdx.x;

    float* xf = &xpad[0][0][0];
    for (int i = tid; i < 3 * 72 * 72; i += 256) xf[i] = 0.f;
    __syncthreads();
    const float* xb = x + b * 3 * HWd;
    for (int i = tid; i < 3 * HWd; i += 256) {
        int c = i >> 12, rem = i & 4095, y = rem >> 6, xx = rem & 63;
        xpad[c][y + 4][xx + 4] = xb[i];
    }
    if (tid < 243) wsh[tid] = conv_w[p * 243 + tid];
    __syncthreads();

    float bias = conv_b[p];
    int y = tid >> 2, x0 = (tid & 3) << 4;
    float acc[16];
    #pragma unroll
    for (int i = 0; i < 16; i++) acc[i] = bias;

    for (int c = 0; c < 3; c++) {
        #pragma unroll 1
        for (int dy = 0; dy < 9; dy++) {
            float r[24];
            #pragma unroll
            for (int t = 0; t < 24; t++) r[t] = xpad[c][y + dy][x0 + t];
            #pragma unroll
            for (int dx = 0; dx < 9; dx++) {
                float wv = wsh[c * 81 + dy * 9 + dx];
                #pragma unroll
                for (int i = 0; i < 16; i++) acc[i] = fmaf(r[i + dx], wv, acc[i]);
            }
        }
    }
    size_t base = (size_t)blk * HWd + y * Wd + x0;
    #pragma unroll
    for (int i = 0; i < 16; i++) {
        float val = fmaxf(acc[i], 0.f);
        u16 h = f2bf(val);
        feat_hi[base + i] = h;
        feat_lo[base + i] = f2bf(val - bf2f(h));
    }
}

// ---------------------------------------------------------------------------
// K2: bf16x3 MFMA GEMM.  C = A@B + bias, A fp32-equivalent as (Ah+Al) bf16,
// B pre-transposed [N][K] as (Bh+Bl).  64x64 tile, BK=64, 4 waves.
// mode 0: Co fp32.  mode 1: Ch/Cl bf16 hi/lo split.
// ---------------------------------------------------------------------------
__global__ __launch_bounds__(256, 4) void gemm_mfma3(
    const u16* __restrict__ Ah, const u16* __restrict__ Al,
    const u16* __restrict__ Bh, const u16* __restrict__ Bl,
    const float* __restrict__ bias,
    float* __restrict__ Co, u16* __restrict__ Ch, u16* __restrict__ Cl,
    int N, int K, int mode) {
    __shared__ u16 sAh[64 * 72], sAl[64 * 72], sBh[64 * 72], sBl[64 * 72];
    int tid = threadIdx.x;
    int w = tid >> 6;
    int L = tid & 63;
    int m16 = L & 15, qd = L >> 4;
    int mb = blockIdx.y * 64, nb = blockIdx.x * 64;

    f32x4 acc[4];
    #pragma unroll
    for (int i = 0; i < 4; i++) acc[i] = (f32x4){0.f, 0.f, 0.f, 0.f};

    int r = tid >> 2, s = tid & 3;
    const u16* pAh = Ah + (size_t)(mb + r) * K + s * 16;
    const u16* pAl = Al + (size_t)(mb + r) * K + s * 16;
    const u16* pBh = Bh + (size_t)(nb + r) * K + s * 16;
    const u16* pBl = Bl + (size_t)(nb + r) * K + s * 16;
    u16* dAh = &sAh[r * 72 + s * 16];
    u16* dAl = &sAl[r * 72 + s * 16];
    u16* dBh = &sBh[r * 72 + s * 16];
    u16* dBl = &sBl[r * 72 + s * 16];

    for (int k0 = 0; k0 < K; k0 += 64) {
        uint4 a0 = *(const uint4*)(pAh + k0);
        uint4 a1 = *(const uint4*)(pAh + k0 + 8);
        uint4 a2 = *(const uint4*)(pAl + k0);
        uint4 a3 = *(const uint4*)(pAl + k0 + 8);
        uint4 b0 = *(const uint4*)(pBh + k0);
        uint4 b1 = *(const uint4*)(pBh + k0 + 8);
        uint4 b2 = *(const uint4*)(pBl + k0);
        uint4 b3 = *(const uint4*)(pBl + k0 + 8);
        __syncthreads();
        *(uint4*)(dAh) = a0; *(uint4*)(dAh + 8) = a1;
        *(uint4*)(dAl) = a2; *(uint4*)(dAl + 8) = a3;
        *(uint4*)(dBh) = b0; *(uint4*)(dBh + 8) = b1;
        *(uint4*)(dBl) = b2; *(uint4*)(dBl + 8) = b3;
        __syncthreads();
        #pragma unroll
        for (int c = 0; c < 2; c++) {
            int ab = (w * 16 + m16) * 72 + c * 32 + qd * 8;
            short8 aH = *(const short8*)&sAh[ab];
            short8 aL = *(const short8*)&sAl[ab];
            #pragma unroll
            for (int ct = 0; ct < 4; ct++) {
                int bb = (ct * 16 + m16) * 72 + c * 32 + qd * 8;
                short8 bH = *(const short8*)&sBh[bb];
                short8 bL = *(const short8*)&sBl[bb];
                acc[ct] = __builtin_amdgcn_mfma_f32_16x16x32_bf16(aH, bH, acc[ct], 0, 0, 0);
                acc[ct] = __builtin_amdgcn_mfma_f32_16x16x32_bf16(aH, bL, acc[ct], 0, 0, 0);
                acc[ct] = __builtin_amdgcn_mfma_f32_16x16x32_bf16(aL, bH, acc[ct], 0, 0, 0);
            }
        }
    }

    #pragma unroll
    for (int ct = 0; ct < 4; ct++) {
        int gc = nb + ct * 16 + m16;
        float bv = bias[gc];
        #pragma unroll
        for (int i = 0; i < 4; i++) {
            int gr = mb + w * 16 + qd * 4 + i;
            float val = acc[ct][i] + bv;
            size_t oi = (size_t)gr * N + gc;
            if (mode == 0) {
                Co[oi] = val;
            } else {
                u16 h = f2bf(val);
                Ch[oi] = h;
                Cl[oi] = f2bf(val - bf2f(h));
            }
        }
    }
}

// ---------------------------------------------------------------------------
// K4: attention. One block per (b,h); thread r = q-row. Online softmax.
// ---------------------------------------------------------------------------
__global__ __launch_bounds__(256) void attention(
    const float* __restrict__ q, const float* __restrict__ k,
    const float* __restrict__ v, float* __restrict__ o) {
    __shared__ float ksh[128][32];
    __shared__ float vsh[128][32];
    int blk = blockIdx.x;          // b*8 + h
    int b = blk >> 3, h = blk & 7;
    int r = threadIdx.x;
    const float rs = 0.17677669529663687f;  // 1/sqrt(32)

    float qr[32];
    const float* qrow = q + ((size_t)(b * Pd + r)) * Ed + h * DHd;
    #pragma unroll
    for (int d = 0; d < 32; d++) qr[d] = qrow[d];

    float m = -1e30f, l = 0.f;
    float oacc[32];
    #pragma unroll
    for (int d = 0; d < 32; d++) oacc[d] = 0.f;

    for (int ch = 0; ch < 2; ch++) {
        __syncthreads();
        {
            int row = r >> 1, dh = (r & 1) << 4;
            const float* srck = k + ((size_t)(b * Pd + ch * 128 + row)) * Ed + h * DHd + dh;
            const float* srcv = v + ((size_t)(b * Pd + ch * 128 + row)) * Ed + h * DHd + dh;
            #pragma unroll
            for (int i = 0; i < 16; i++) { ksh[row][dh + i] = srck[i]; vsh[row][dh + i] = srcv[i]; }
        }
        __syncthreads();
        for (int kk = 0; kk < 128; kk++) {
            float s = 0.f;
            #pragma unroll
            for (int d = 0; d < 32; d++) s = fmaf(qr[d], ksh[kk][d], s);
            s *= rs;
            float mnew = fmaxf(m, s);
            float scale = __expf(m - mnew);
            float pexp = __expf(s - mnew);
            l = l * scale + pexp;
            #pragma unroll
            for (int d = 0; d < 32; d++) oacc[d] = fmaf(oacc[d], scale, pexp * vsh[kk][d]);
            m = mnew;
        }
    }
    float rinv = 1.f / l;
    float* orow = o + ((size_t)(b * Pd + r)) * Ed + h * DHd;
    #pragma unroll
    for (int d = 0; d < 32; d++) orow[d] = oacc[d] * rinv;
}

// ---------------------------------------------------------------------------
// K5: fused head. One wave per (b,p): tp = tanh(o@M2 + h0); pos embed; patches.
// ---------------------------------------------------------------------------
#define PATCH_OUT 995328   // 16*256*243
__global__ __launch_bounds__(256) void head_kernel(
    const float* __restrict__ o, const float* __restrict__ M2,
    const float* __restrict__ h0, const float* __restrict__ pos_w,
    const float* __restrict__ pos_b, const float* __restrict__ x,
    float* __restrict__ out) {
    int w = threadIdx.x >> 6, lane = threadIdx.x & 63;
    int bp = blockIdx.x * 4 + w;
    int b = bp >> 8;

    const float* orow = o + (size_t)bp * Ed;
    float4 o4 = *(const float4*)(orow + lane * 4);
    int e0 = lane * 4;
    float s0 = o4.x * M2[2 * e0 + 0] + o4.y * M2[2 * e0 + 2] + o4.z * M2[2 * e0 + 4] + o4.w * M2[2 * e0 + 6];
    float s1 = o4.x * M2[2 * e0 + 1] + o4.y * M2[2 * e0 + 3] + o4.z * M2[2 * e0 + 5] + o4.w * M2[2 * e0 + 7];
    #pragma unroll
    for (int off = 32; off; off >>= 1) { s0 += __shfl_xor(s0, off); s1 += __shfl_xor(s1, off); }

    float tx = tanhf(s0 + h0[0]);
    float ty = tanhf(s1 + h0[1]);

    {
        float pv = tx * pos_w[lane] + ty * pos_w[64 + lane] + pos_b[lane];
        out[PATCH_OUT + bp * POSDd + lane] = pv;
    }

    const float* xb = x + b * 3 * HWd;
    #pragma unroll
    for (int s = 0; s < 4; s++) {
        int idx = s * 64 + lane;
        if (idx < 243) {
            int c = idx / 81;
            int rem = idx - c * 81;
            int iy = rem / 9;
            int jx = rem - iy * 9;
            float basex = (2.f * jx + 1.f) / 9.f - 1.f;
            float basey = (2.f * iy + 1.f) / 9.f - 1.f;
            float gx = 0.140625f * basex + tx;
            float gy = 0.140625f * basey + ty;
            float ix  = ((gx + 1.f) * 64.f - 1.f) * 0.5f;
            float iyf = ((gy + 1.f) * 64.f - 1.f) * 0.5f;
            float x0f = floorf(ix), y0f = floorf(iyf);
            float wx = ix - x0f, wy = iyf - y0f;
            int x0i = min(max((int)x0f, 0), 63);
            int x1i = min(max((int)x0f + 1, 0), 63);
            int y0i = min(max((int)y0f, 0), 63);
            int y1i = min(max((int)y0f + 1, 0), 63);
            const float* xc = xb + c * HWd;
            float v00 = xc[y0i * Wd + x0i];
            float v01 = xc[y0i * Wd + x1i];
            float v10 = xc[y1i * Wd + x0i];
            float v11 = xc[y1i * Wd + x1i];
            float val = v00 * (1.f - wx) * (1.f - wy) + v01 * wx * (1.f - wy)
                      + v10 * (1.f - wx) * wy + v11 * wx * wy;
            out[bp * 243 + idx] = val;
        }
    }
}

// ---------------------------------------------------------------------------
extern "C" void kernel_launch(void* const* d_in, const int* in_sizes, int n_in,
                              void* d_out, int out_size, void* d_ws, size_t ws_size,
                              hipStream_t stream) {
    (void)in_sizes; (void)n_in; (void)out_size;
    const float* x      = (const float*)d_in[0];
    const float* conv_w = (const float*)d_in[1];
    const float* conv_b = (const float*)d_in[2];
    const float* in_w   = (const float*)d_in[3];
    const float* in_b   = (const float*)d_in[4];
    const float* wq     = (const float*)d_in[5];
    const float* bq     = (const float*)d_in[6];
    const float* wk     = (const float*)d_in[7];
    const float* bk     = (const float*)d_in[8];
    const float* wv     = (const float*)d_in[9];
    const float* bv     = (const float*)d_in[10];
    const float* wo     = (const float*)d_in[11];
    const float* bo     = (const float*)d_in[12];
    const float* out_w  = (const float*)d_in[13];
    const float* out_b  = (const float*)d_in[14];
    const float* fc_w   = (const float*)d_in[15];
    const float* fc_b   = (const float*)d_in[16];
    const float* pos_w  = (const float*)d_in[17];
    const float* pos_b  = (const float*)d_in[18];

    // ws budget: feat hi/lo = 2*CB MB-elems, tok hi/lo + in_w_t hi/lo = 4 MB-elems,
    // wq/wk/wv_t = 6*65536, then q/k/v/o fp32 + G/M2/h0.
    int CB = 16;
    for (;;) {
        size_t need = (size_t)(2 * CB + 4) * 1048576 * 2 + 6 * 65536 * 2
                    + 4ull * 1048576 * 4 + 4096;
        if (need <= ws_size || CB == 1) break;
        CB >>= 1;
    }
    int nchunks = 16 / CB;

    char* base = (char*)d_ws;
    u16* feat_hi = (u16*)base;
    u16* feat_lo = feat_hi + (size_t)CB * 1048576;
    u16* tok_hi  = feat_lo + (size_t)CB * 1048576;
    u16* tok_lo  = tok_hi + 1048576;
    u16* inw_h   = tok_lo + 1048576;
    u16* inw_l   = inw_h + 1048576;
    u16* wqt_h   = inw_l + 1048576;
    u16* wqt_l   = wqt_h + 65536;
    u16* wkt_h   = wqt_l + 65536;
    u16* wkt_l   = wkt_h + 65536;
    u16* wvt_h   = wkt_l + 65536;
    u16* wvt_l   = wvt_h + 65536;
    float* q     = (float*)(wvt_l + 65536);
    float* k     = q + 1048576;
    float* v     = k + 1048576;
    float* o     = v + 1048576;
    float* G     = o + 1048576;
    float* M2    = G + 512;
    float* h0    = M2 + 512;
    float* out   = (float*)d_out;

    hipLaunchKernelGGL(precompute_G, dim3(258), dim3(64), 0, stream,
                       out_w, fc_w, out_b, fc_b, G, h0);
    hipLaunchKernelGGL(precompute_M2, dim3(1), dim3(256), 0, stream,
                       wo, bo, G, M2, h0);
    hipLaunchKernelGGL(prep_weight, dim3(4096), dim3(256), 0, stream,
                       in_w, inw_h, inw_l, 4096);
    hipLaunchKernelGGL(prep_weight, dim3(256), dim3(256), 0, stream,
                       wq, wqt_h, wqt_l, 256);
    hipLaunchKernelGGL(prep_weight, dim3(256), dim3(256), 0, stream,
                       wk, wkt_h, wkt_l, 256);
    hipLaunchKernelGGL(prep_weight, dim3(256), dim3(256), 0, stream,
                       wv, wvt_h, wvt_l, 256);

    for (int c = 0; c < nchunks; ++c) {
        hipLaunchKernelGGL(conv_relu, dim3(CB * 256), dim3(256), 0, stream,
                           x + (size_t)c * CB * 3 * HWd, conv_w, conv_b,
                           feat_hi, feat_lo);
        hipLaunchKernelGGL(gemm_mfma3, dim3(4, CB * 4), dim3(256), 0, stream,
                           feat_hi, feat_lo, inw_h, inw_l, in_b,
                           (float*)nullptr,
                           tok_hi + (size_t)c * CB * 65536,
                           tok_lo + (size_t)c * CB * 65536,
                           256, 4096, 1);
    }
    hipLaunchKernelGGL(gemm_mfma3, dim3(4, 64), dim3(256), 0, stream,
                       tok_hi, tok_lo, wqt_h, wqt_l, bq,
                       q, (u16*)nullptr, (u16*)nullptr, 256, 256, 0);
    hipLaunchKernelGGL(gemm_mfma3, dim3(4, 64), dim3(256), 0, stream,
                       tok_hi, tok_lo, wkt_h, wkt_l, bk,
                       k, (u16*)nullptr, (u16*)nullptr, 256, 256, 0);
    hipLaunchKernelGGL(gemm_mfma3, dim3(4, 64), dim3(256), 0, stream,
                       tok_hi, tok_lo, wvt_h, wvt_l, bv,
                       v, (u16*)nullptr, (u16*)nullptr, 256, 256, 0);
    hipLaunchKernelGGL(attention, dim3(128), dim3(256), 0, stream, q, k, v, o);
    hipLaunchKernelGGL(head_kernel, dim3(1024), dim3(256), 0, stream,
                       o, M2, h0, pos_w, pos_b, x, out);
}

// Round 5
// 509.923 us; speedup vs baseline: 1.5949x; 1.1454x over previous
//
#include <hip/hip_runtime.h>
#include <hip/hip_bf16.h>

// Problem dims
#define Bd 16
#define Cd 3
#define Hd 64
#define Wd 64
#define Pd 256
#define PSd 9
#define Ed 256
#define NHd 8
#define DHd 32
#define HWd 4096
#define POSDd 64

typedef unsigned short u16;
typedef short short8 __attribute__((ext_vector_type(8)));
typedef float f32x4 __attribute__((ext_vector_type(4)));

__device__ __forceinline__ float bf2f(u16 u) {
    union { unsigned int i; float f; } c; c.i = ((unsigned int)u) << 16; return c.f;
}
__device__ __forceinline__ u16 f2bf(float f) {
    unsigned int x = __float_as_uint(f);
    unsigned int r = (x + 0x7fffu + ((x >> 16) & 1u)) >> 16;
    return (u16)r;
}

// ---------------------------------------------------------------------------
// K0a: G[e][j] = sum_hw out_w[e,hw] * fc_w[hw,j]   (e<256, j<2)
//      blocks 256,257: h0[j] = sum_hw out_b[hw]*fc_w[hw,j] + fc_b[j]
// ---------------------------------------------------------------------------
__global__ __launch_bounds__(64) void precompute_G(
    const float* __restrict__ out_w, const float* __restrict__ fc_w,
    const float* __restrict__ out_b, const float* __restrict__ fc_b,
    float* __restrict__ G, float* __restrict__ h0) {
    int blk = blockIdx.x, lane = threadIdx.x;
    if (blk < 256) {
        int e = blk;
        float a0 = 0.f, a1 = 0.f;
        for (int i = lane; i < HWd; i += 64) {
            float a = out_w[e * HWd + i];
            a0 += a * fc_w[2 * i];
            a1 += a * fc_w[2 * i + 1];
        }
        #pragma unroll
        for (int off = 32; off; off >>= 1) { a0 += __shfl_xor(a0, off); a1 += __shfl_xor(a1, off); }
        if (lane == 0) { G[2 * e] = a0; G[2 * e + 1] = a1; }
    } else {
        int j = blk - 256;
        float a = 0.f;
        for (int i = lane; i < HWd; i += 64) a += out_b[i] * fc_w[2 * i + j];
        #pragma unroll
        for (int off = 32; off; off >>= 1) a += __shfl_xor(a, off);
        if (lane == 0) h0[j] = a + fc_b[j];
    }
}

// ---------------------------------------------------------------------------
// K0b: M2[e][j] = sum_f wo[e,f] * G[f][j];  h0[j] += sum_e bo[e]*G[e][j]
// ---------------------------------------------------------------------------
__global__ __launch_bounds__(256) void precompute_M2(
    const float* __restrict__ wo, const float* __restrict__ bo,
    const float* __restrict__ G, float* __restrict__ M2, float* __restrict__ h0) {
    int e = threadIdx.x;
    float m0 = 0.f, m1 = 0.f;
    for (int f = 0; f < Ed; f++) {
        float wv = wo[e * Ed + f];
        m0 += wv * G[2 * f];
        m1 += wv * G[2 * f + 1];
    }
    M2[2 * e] = m0;
    M2[2 * e + 1] = m1;
    if (e < 2) {
        float hh = 0.f;
        for (int f = 0; f < Ed; f++) hh += bo[f] * G[2 * f + e];
        h0[e] += hh;
    }
}

// ---------------------------------------------------------------------------
// prep: W[K][N] fp32 -> Th/Tl[N][K] bf16 hi/lo, LDS-tiled transpose, both
// sides coalesced.  grid = (K/64, N/64), 256 threads.
// ---------------------------------------------------------------------------
__global__ __launch_bounds__(256) void prep_weight_t(
    const float* __restrict__ W, u16* __restrict__ Th, u16* __restrict__ Tl,
    int K, int N) {
    __shared__ u16 th[64][65];
    __shared__ u16 tl[64][65];
    int k0 = blockIdx.x * 64, n0 = blockIdx.y * 64;
    int col = threadIdx.x & 63, r4 = threadIdx.x >> 6;
    #pragma unroll
    for (int i = 0; i < 16; i++) {
        int kr = 4 * i + r4;
        float v = W[(size_t)(k0 + kr) * N + n0 + col];
        u16 h = f2bf(v);
        th[col][kr] = h;
        tl[col][kr] = f2bf(v - bf2f(h));
    }
    __syncthreads();
    #pragma unroll
    for (int i = 0; i < 16; i++) {
        int nr = 4 * i + r4;
        Th[(size_t)(n0 + nr) * K + k0 + col] = th[nr][col];
        Tl[(size_t)(n0 + nr) * K + k0 + col] = tl[nr][col];
    }
}

// concat bq,bk,bv -> b3[768]
__global__ __launch_bounds__(256) void concat_bias(
    const float* __restrict__ bq, const float* __restrict__ bk,
    const float* __restrict__ bv, float* __restrict__ b3) {
    int t = threadIdx.x;
    b3[t] = bq[t]; b3[256 + t] = bk[t]; b3[512 + t] = bv[t];
}

// ---------------------------------------------------------------------------
// K1: conv 9x9 pad4 + bias + relu -> feat bf16 hi/lo [bp][hw].
// LDS row stride 73 (odd): 16 rows x 4 col-groups of 64 lanes map to all 32
// banks at exactly 2 lanes/bank (free) instead of 16-way conflicts at 72.
// ---------------------------------------------------------------------------
__global__ __launch_bounds__(256) void conv_relu(
    const float* __restrict__ x, const float* __restrict__ conv_w,
    const float* __restrict__ conv_b,
    u16* __restrict__ feat_hi, u16* __restrict__ feat_lo) {
    __shared__ float xpad[3][72][73];
    __shared__ float wsh[243];
    int blk = blockIdx.x;
    int b = blk >> 8, p = blk & 255;
    int tid = threadIdx.x;

    float* xf = &xpad[0][0][0];
    for (int i = tid; i < 3 * 72 * 73; i += 256) xf[i] = 0.f;
    __syncthreads();
    const float* xb = x + b * 3 * HWd;
    for (int i = tid; i < 3 * HWd; i += 256) {
        int c = i >> 12, rem = i & 4095, y = rem >> 6, xx = rem & 63;
        xpad[c][y + 4][xx + 4] = xb[i];
    }
    if (tid < 243) wsh[tid] = conv_w[p * 243 + tid];
    __syncthreads();

    float bias = conv_b[p];
    int y = tid >> 2, x0 = (tid & 3) << 4;
    float acc[16];
    #pragma unroll
    for (int i = 0; i < 16; i++) acc[i] = bias;

    for (int c = 0; c < 3; c++) {
        #pragma unroll 1
        for (int dy = 0; dy < 9; dy++) {
            float r[24];
            #pragma unroll
            for (int t = 0; t < 24; t++) r[t] = xpad[c][y + dy][x0 + t];
            #pragma unroll
            for (int dx = 0; dx < 9; dx++) {
                float wv = wsh[c * 81 + dy * 9 + dx];
                #pragma unroll
                for (int i = 0; i < 16; i++) acc[i] = fmaf(r[i + dx], wv, acc[i]);
            }
        }
    }
    size_t base = (size_t)blk * HWd + y * Wd + x0;
    #pragma unroll
    for (int i = 0; i < 16; i++) {
        float val = fmaxf(acc[i], 0.f);
        u16 h = f2bf(val);
        feat_hi[base + i] = h;
        feat_lo[base + i] = f2bf(val - bf2f(h));
    }
}

// ---------------------------------------------------------------------------
// K2: bf16x3 MFMA GEMM.  C = A@B + bias, A as (Ah+Al) bf16, B pre-transposed
// [N][K] as (Bh+Bl).  64x64 tile, BK=64, 4 waves.
// mode 0: Co fp32.  mode 1: Ch/Cl bf16 hi/lo split.
// ---------------------------------------------------------------------------
__global__ __launch_bounds__(256, 4) void gemm_mfma3(
    const u16* __restrict__ Ah, const u16* __restrict__ Al,
    const u16* __restrict__ Bh, const u16* __restrict__ Bl,
    const float* __restrict__ bias,
    float* __restrict__ Co, u16* __restrict__ Ch, u16* __restrict__ Cl,
    int N, int K, int mode) {
    __shared__ u16 sAh[64 * 72], sAl[64 * 72], sBh[64 * 72], sBl[64 * 72];
    int tid = threadIdx.x;
    int w = tid >> 6;
    int L = tid & 63;
    int m16 = L & 15, qd = L >> 4;
    int mb = blockIdx.y * 64, nb = blockIdx.x * 64;

    f32x4 acc[4];
    #pragma unroll
    for (int i = 0; i < 4; i++) acc[i] = (f32x4){0.f, 0.f, 0.f, 0.f};

    int r = tid >> 2, s = tid & 3;
    const u16* pAh = Ah + (size_t)(mb + r) * K + s * 16;
    const u16* pAl = Al + (size_t)(mb + r) * K + s * 16;
    const u16* pBh = Bh + (size_t)(nb + r) * K + s * 16;
    const u16* pBl = Bl + (size_t)(nb + r) * K + s * 16;
    u16* dAh = &sAh[r * 72 + s * 16];
    u16* dAl = &sAl[r * 72 + s * 16];
    u16* dBh = &sBh[r * 72 + s * 16];
    u16* dBl = &sBl[r * 72 + s * 16];

    for (int k0 = 0; k0 < K; k0 += 64) {
        uint4 a0 = *(const uint4*)(pAh + k0);
        uint4 a1 = *(const uint4*)(pAh + k0 + 8);
        uint4 a2 = *(const uint4*)(pAl + k0);
        uint4 a3 = *(const uint4*)(pAl + k0 + 8);
        uint4 b0 = *(const uint4*)(pBh + k0);
        uint4 b1 = *(const uint4*)(pBh + k0 + 8);
        uint4 b2 = *(const uint4*)(pBl + k0);
        uint4 b3 = *(const uint4*)(pBl + k0 + 8);
        __syncthreads();
        *(uint4*)(dAh) = a0; *(uint4*)(dAh + 8) = a1;
        *(uint4*)(dAl) = a2; *(uint4*)(dAl + 8) = a3;
        *(uint4*)(dBh) = b0; *(uint4*)(dBh + 8) = b1;
        *(uint4*)(dBl) = b2; *(uint4*)(dBl + 8) = b3;
        __syncthreads();
        #pragma unroll
        for (int c = 0; c < 2; c++) {
            int ab = (w * 16 + m16) * 72 + c * 32 + qd * 8;
            short8 aH = *(const short8*)&sAh[ab];
            short8 aL = *(const short8*)&sAl[ab];
            #pragma unroll
            for (int ct = 0; ct < 4; ct++) {
                int bb = (ct * 16 + m16) * 72 + c * 32 + qd * 8;
                short8 bH = *(const short8*)&sBh[bb];
                short8 bL = *(const short8*)&sBl[bb];
                acc[ct] = __builtin_amdgcn_mfma_f32_16x16x32_bf16(aH, bH, acc[ct], 0, 0, 0);
                acc[ct] = __builtin_amdgcn_mfma_f32_16x16x32_bf16(aH, bL, acc[ct], 0, 0, 0);
                acc[ct] = __builtin_amdgcn_mfma_f32_16x16x32_bf16(aL, bH, acc[ct], 0, 0, 0);
            }
        }
    }

    #pragma unroll
    for (int ct = 0; ct < 4; ct++) {
        int gc = nb + ct * 16 + m16;
        float bv = bias[gc];
        #pragma unroll
        for (int i = 0; i < 4; i++) {
            int gr = mb + w * 16 + qd * 4 + i;
            float val = acc[ct][i] + bv;
            size_t oi = (size_t)gr * N + gc;
            if (mode == 0) {
                Co[oi] = val;
            } else {
                u16 h = f2bf(val);
                Ch[oi] = h;
                Cl[oi] = f2bf(val - bf2f(h));
            }
        }
    }
}

// ---------------------------------------------------------------------------
// K4: attention over fused qkv[4096][768] (q|k|v per row).
// One block per (b,h); thread r = q-row. Online softmax.
// ---------------------------------------------------------------------------
__global__ __launch_bounds__(256) void attention(
    const float* __restrict__ qkv, float* __restrict__ o) {
    __shared__ float ksh[128][32];
    __shared__ float vsh[128][32];
    int blk = blockIdx.x;          // b*8 + h
    int b = blk >> 3, h = blk & 7;
    int r = threadIdx.x;
    const float rs = 0.17677669529663687f;  // 1/sqrt(32)

    float qr[32];
    const float* qrow = qkv + ((size_t)(b * Pd + r)) * 768 + h * DHd;
    #pragma unroll
    for (int d = 0; d < 32; d++) qr[d] = qrow[d];

    float m = -1e30f, l = 0.f;
    float oacc[32];
    #pragma unroll
    for (int d = 0; d < 32; d++) oacc[d] = 0.f;

    for (int ch = 0; ch < 2; ch++) {
        __syncthreads();
        {
            int row = r >> 1, dh = (r & 1) << 4;
            const float* srck = qkv + ((size_t)(b * Pd + ch * 128 + row)) * 768 + 256 + h * DHd + dh;
            const float* srcv = srck + 256;
            #pragma unroll
            for (int i = 0; i < 16; i++) { ksh[row][dh + i] = srck[i]; vsh[row][dh + i] = srcv[i]; }
        }
        __syncthreads();
        for (int kk = 0; kk < 128; kk++) {
            float s = 0.f;
            #pragma unroll
            for (int d = 0; d < 32; d++) s = fmaf(qr[d], ksh[kk][d], s);
            s *= rs;
            float mnew = fmaxf(m, s);
            float scale = __expf(m - mnew);
            float pexp = __expf(s - mnew);
            l = l * scale + pexp;
            #pragma unroll
            for (int d = 0; d < 32; d++) oacc[d] = fmaf(oacc[d], scale, pexp * vsh[kk][d]);
            m = mnew;
        }
    }
    float rinv = 1.f / l;
    float* orow = o + ((size_t)(b * Pd + r)) * Ed + h * DHd;
    #pragma unroll
    for (int d = 0; d < 32; d++) orow[d] = oacc[d] * rinv;
}

// ---------------------------------------------------------------------------
// K5: fused head. One wave per (b,p): tp = tanh(o@M2 + h0); pos embed; patches.
// ---------------------------------------------------------------------------
#define PATCH_OUT 995328   // 16*256*243
__global__ __launch_bounds__(256) void head_kernel(
    const float* __restrict__ o, const float* __restrict__ M2,
    const float* __restrict__ h0, const float* __restrict__ pos_w,
    const float* __restrict__ pos_b, const float* __restrict__ x,
    float* __restrict__ out) {
    int w = threadIdx.x >> 6, lane = threadIdx.x & 63;
    int bp = blockIdx.x * 4 + w;
    int b = bp >> 8;

    const float* orow = o + (size_t)bp * Ed;
    float4 o4 = *(const float4*)(orow + lane * 4);
    int e0 = lane * 4;
    float s0 = o4.x * M2[2 * e0 + 0] + o4.y * M2[2 * e0 + 2] + o4.z * M2[2 * e0 + 4] + o4.w * M2[2 * e0 + 6];
    float s1 = o4.x * M2[2 * e0 + 1] + o4.y * M2[2 * e0 + 3] + o4.z * M2[2 * e0 + 5] + o4.w * M2[2 * e0 + 7];
    #pragma unroll
    for (int off = 32; off; off >>= 1) { s0 += __shfl_xor(s0, off); s1 += __shfl_xor(s1, off); }

    float tx = tanhf(s0 + h0[0]);
    float ty = tanhf(s1 + h0[1]);

    {
        float pv = tx * pos_w[lane] + ty * pos_w[64 + lane] + pos_b[lane];
        out[PATCH_OUT + bp * POSDd + lane] = pv;
    }

    const float* xb = x + b * 3 * HWd;
    #pragma unroll
    for (int s = 0; s < 4; s++) {
        int idx = s * 64 + lane;
        if (idx < 243) {
            int c = idx / 81;
            int rem = idx - c * 81;
            int iy = rem / 9;
            int jx = rem - iy * 9;
            float basex = (2.f * jx + 1.f) / 9.f - 1.f;
            float basey = (2.f * iy + 1.f) / 9.f - 1.f;
            float gx = 0.140625f * basex + tx;
            float gy = 0.140625f * basey + ty;
            float ix  = ((gx + 1.f) * 64.f - 1.f) * 0.5f;
            float iyf = ((gy + 1.f) * 64.f - 1.f) * 0.5f;
            float x0f = floorf(ix), y0f = floorf(iyf);
            float wx = ix - x0f, wy = iyf - y0f;
            int x0i = min(max((int)x0f, 0), 63);
            int x1i = min(max((int)x0f + 1, 0), 63);
            int y0i = min(max((int)y0f, 0), 63);
            int y1i = min(max((int)y0f + 1, 0), 63);
            const float* xc = xb + c * HWd;
            float v00 = xc[y0i * Wd + x0i];
            float v01 = xc[y0i * Wd + x1i];
            float v10 = xc[y1i * Wd + x0i];
            float v11 = xc[y1i * Wd + x1i];
            float val = v00 * (1.f - wx) * (1.f - wy) + v01 * wx * (1.f - wy)
                      + v10 * (1.f - wx) * wy + v11 * wx * wy;
            out[bp * 243 + idx] = val;
        }
    }
}

// ---------------------------------------------------------------------------
extern "C" void kernel_launch(void* const* d_in, const int* in_sizes, int n_in,
                              void* d_out, int out_size, void* d_ws, size_t ws_size,
                              hipStream_t stream) {
    (void)in_sizes; (void)n_in; (void)out_size;
    const float* x      = (const float*)d_in[0];
    const float* conv_w = (const float*)d_in[1];
    const float* conv_b = (const float*)d_in[2];
    const float* in_w   = (const float*)d_in[3];
    const float* in_b   = (const float*)d_in[4];
    const float* wq     = (const float*)d_in[5];
    const float* bq     = (const float*)d_in[6];
    const float* wk     = (const float*)d_in[7];
    const float* bk     = (const float*)d_in[8];
    const float* wv     = (const float*)d_in[9];
    const float* bv     = (const float*)d_in[10];
    const float* wo     = (const float*)d_in[11];
    const float* bo     = (const float*)d_in[12];
    const float* out_w  = (const float*)d_in[13];
    const float* out_b  = (const float*)d_in[14];
    const float* fc_w   = (const float*)d_in[15];
    const float* fc_b   = (const float*)d_in[16];
    const float* pos_w  = (const float*)d_in[17];
    const float* pos_b  = (const float*)d_in[18];

    // ws budget (u16): feat 2*CB*1M, tok 2*1M, inw_t 2*1M, wqkv_t 2*196608.
    // fp32: bqkv 768, qkv 3M, o 1M, G/M2/h0 ~1K.
    int CB = 16;
    for (;;) {
        size_t need = ((size_t)(2 * CB + 4) * 1048576 + 2 * 196608) * 2
                    + (768 + 3145728 + 1048576 + 2048) * 4;
        if (need <= ws_size || CB == 1) break;
        CB >>= 1;
    }
    int nchunks = 16 / CB;

    char* base = (char*)d_ws;
    u16* feat_hi = (u16*)base;
    u16* feat_lo = feat_hi + (size_t)CB * 1048576;
    u16* tok_hi  = feat_lo + (size_t)CB * 1048576;
    u16* tok_lo  = tok_hi + 1048576;
    u16* inw_h   = tok_lo + 1048576;
    u16* inw_l   = inw_h + 1048576;
    u16* wqkv_h  = inw_l + 1048576;
    u16* wqkv_l  = wqkv_h + 196608;
    float* bqkv  = (float*)(wqkv_l + 196608);
    float* qkv   = bqkv + 768;
    float* o     = qkv + 3145728;
    float* G     = o + 1048576;
    float* M2    = G + 512;
    float* h0    = M2 + 512;
    float* out   = (float*)d_out;

    hipLaunchKernelGGL(precompute_G, dim3(258), dim3(64), 0, stream,
                       out_w, fc_w, out_b, fc_b, G, h0);
    hipLaunchKernelGGL(precompute_M2, dim3(1), dim3(256), 0, stream,
                       wo, bo, G, M2, h0);
    hipLaunchKernelGGL(prep_weight_t, dim3(64, 4), dim3(256), 0, stream,
                       in_w, inw_h, inw_l, 4096, 256);
    hipLaunchKernelGGL(prep_weight_t, dim3(4, 4), dim3(256), 0, stream,
                       wq, wqkv_h, wqkv_l, 256, 256);
    hipLaunchKernelGGL(prep_weight_t, dim3(4, 4), dim3(256), 0, stream,
                       wk, wqkv_h + 256 * 256, wqkv_l + 256 * 256, 256, 256);
    hipLaunchKernelGGL(prep_weight_t, dim3(4, 4), dim3(256), 0, stream,
                       wv, wqkv_h + 512 * 256, wqkv_l + 512 * 256, 256, 256);
    hipLaunchKernelGGL(concat_bias, dim3(1), dim3(256), 0, stream,
                       bq, bk, bv, bqkv);

    for (int c = 0; c < nchunks; ++c) {
        hipLaunchKernelGGL(conv_relu, dim3(CB * 256), dim3(256), 0, stream,
                           x + (size_t)c * CB * 3 * HWd, conv_w, conv_b,
                           feat_hi, feat_lo);
        hipLaunchKernelGGL(gemm_mfma3, dim3(4, CB * 4), dim3(256), 0, stream,
                           feat_hi, feat_lo, inw_h, inw_l, in_b,
                           (float*)nullptr,
                           tok_hi + (size_t)c * CB * 65536,
                           tok_lo + (size_t)c * CB * 65536,
                           256, 4096, 1);
    }
    // fused q|k|v GEMM: C[4096][768]
    hipLaunchKernelGGL(gemm_mfma3, dim3(12, 64), dim3(256), 0, stream,
                       tok_hi, tok_lo, wqkv_h, wqkv_l, bqkv,
                       qkv, (u16*)nullptr, (u16*)nullptr, 768, 256, 0);
    hipLaunchKernelGGL(attention, dim3(128), dim3(256), 0, stream, qkv, o);
    hipLaunchKernelGGL(head_kernel, dim3(1024), dim3(256), 0, stream,
                       o, M2, h0, pos_w, pos_b, x, out);
}

// Round 6
// 436.119 us; speedup vs baseline: 1.8648x; 1.1692x over previous
//
#include <hip/hip_runtime.h>
#include <hip/hip_bf16.h>

// Problem dims
#define Bd 16
#define Cd 3
#define Hd 64
#define Wd 64
#define Pd 256
#define PSd 9
#define Ed 256
#define NHd 8
#define DHd 32
#define HWd 4096
#define POSDd 64

typedef unsigned short u16;
typedef short short8 __attribute__((ext_vector_type(8)));
typedef float f32x4 __attribute__((ext_vector_type(4)));

__device__ __forceinline__ float bf2f(u16 u) {
    union { unsigned int i; float f; } c; c.i = ((unsigned int)u) << 16; return c.f;
}
__device__ __forceinline__ u16 f2bf(float f) {
    unsigned int x = __float_as_uint(f);
    unsigned int r = (x + 0x7fffu + ((x >> 16) & 1u)) >> 16;
    return (u16)r;
}

// ---------------------------------------------------------------------------
// K0a: G[e][j] = sum_hw out_w[e,hw] * fc_w[hw,j]   (e<256, j<2)
//      blocks 256,257: h0[j] = sum_hw out_b[hw]*fc_w[hw,j] + fc_b[j]
// ---------------------------------------------------------------------------
__global__ __launch_bounds__(64) void precompute_G(
    const float* __restrict__ out_w, const float* __restrict__ fc_w,
    const float* __restrict__ out_b, const float* __restrict__ fc_b,
    float* __restrict__ G, float* __restrict__ h0) {
    int blk = blockIdx.x, lane = threadIdx.x;
    if (blk < 256) {
        int e = blk;
        float a0 = 0.f, a1 = 0.f;
        for (int i = lane; i < HWd; i += 64) {
            float a = out_w[e * HWd + i];
            a0 += a * fc_w[2 * i];
            a1 += a * fc_w[2 * i + 1];
        }
        #pragma unroll
        for (int off = 32; off; off >>= 1) { a0 += __shfl_xor(a0, off); a1 += __shfl_xor(a1, off); }
        if (lane == 0) { G[2 * e] = a0; G[2 * e + 1] = a1; }
    } else {
        int j = blk - 256;
        float a = 0.f;
        for (int i = lane; i < HWd; i += 64) a += out_b[i] * fc_w[2 * i + j];
        #pragma unroll
        for (int off = 32; off; off >>= 1) a += __shfl_xor(a, off);
        if (lane == 0) h0[j] = a + fc_b[j];
    }
}

// ---------------------------------------------------------------------------
// K0b (parallel): block e<256: M2[e][:] = sum_f wo[e,f]*G[f][:]
//                 blocks 256,257: h0[j] += sum_e bo[e]*G[e][j]
// ---------------------------------------------------------------------------
__global__ __launch_bounds__(64) void precompute_M2(
    const float* __restrict__ wo, const float* __restrict__ bo,
    const float* __restrict__ G, float* __restrict__ M2, float* __restrict__ h0) {
    int blk = blockIdx.x, lane = threadIdx.x;
    if (blk < 256) {
        float m0 = 0.f, m1 = 0.f;
        for (int f = lane; f < Ed; f += 64) {
            float wv = wo[blk * Ed + f];
            m0 += wv * G[2 * f];
            m1 += wv * G[2 * f + 1];
        }
        #pragma unroll
        for (int off = 32; off; off >>= 1) { m0 += __shfl_xor(m0, off); m1 += __shfl_xor(m1, off); }
        if (lane == 0) { M2[2 * blk] = m0; M2[2 * blk + 1] = m1; }
    } else {
        int j = blk - 256;
        float hh = 0.f;
        for (int f = lane; f < Ed; f += 64) hh += bo[f] * G[2 * f + j];
        #pragma unroll
        for (int off = 32; off; off >>= 1) hh += __shfl_xor(hh, off);
        if (lane == 0) h0[j] += hh;
    }
}

// ---------------------------------------------------------------------------
// prep: W[K][N] fp32 -> Th/Tl[N][K] bf16 hi/lo, LDS-tiled transpose.
// ---------------------------------------------------------------------------
__global__ __launch_bounds__(256) void prep_weight_t(
    const float* __restrict__ W, u16* __restrict__ Th, u16* __restrict__ Tl,
    int K, int N) {
    __shared__ u16 th[64][65];
    __shared__ u16 tl[64][65];
    int k0 = blockIdx.x * 64, n0 = blockIdx.y * 64;
    int col = threadIdx.x & 63, r4 = threadIdx.x >> 6;
    #pragma unroll
    for (int i = 0; i < 16; i++) {
        int kr = 4 * i + r4;
        float v = W[(size_t)(k0 + kr) * N + n0 + col];
        u16 h = f2bf(v);
        th[col][kr] = h;
        tl[col][kr] = f2bf(v - bf2f(h));
    }
    __syncthreads();
    #pragma unroll
    for (int i = 0; i < 16; i++) {
        int nr = 4 * i + r4;
        Th[(size_t)(n0 + nr) * K + k0 + col] = th[nr][col];
        Tl[(size_t)(n0 + nr) * K + k0 + col] = tl[nr][col];
    }
}

// concat bq,bk,bv -> b3[768]
__global__ __launch_bounds__(256) void concat_bias(
    const float* __restrict__ bq, const float* __restrict__ bk,
    const float* __restrict__ bv, float* __restrict__ b3) {
    int t = threadIdx.x;
    b3[t] = bq[t]; b3[256 + t] = bk[t]; b3[512 + t] = bv[t];
}

// ---------------------------------------------------------------------------
// K1: conv 9x9 pad4 + bias + relu -> feat bf16 hi/lo [bp][hw].
// 4 output channels per block: each LDS read amortized over 4 p's (the conv
// was at the LDS-read-BW roofline at 1 p/block).  One channel of x staged at
// a time (21 KB, stride 73 = conflict-free for b32).  Weights read via
// uniform global loads (scalar s_load path, zero LDS traffic).
// ---------------------------------------------------------------------------
__global__ __launch_bounds__(256, 4) void conv_relu(
    const float* __restrict__ x, const float* __restrict__ conv_w,
    const float* __restrict__ conv_b,
    u16* __restrict__ feat_hi, u16* __restrict__ feat_lo) {
    __shared__ float xpad[72][73];
    int blk = blockIdx.x;
    int b = blk >> 6, p0 = (blk & 63) << 2;
    int tid = threadIdx.x;

    // zero whole pad once; interior is overwritten each channel, borders stay 0
    float* xf = &xpad[0][0];
    for (int i = tid; i < 72 * 73; i += 256) xf[i] = 0.f;

    float acc[4][16];
    #pragma unroll
    for (int pp = 0; pp < 4; pp++) {
        float bias = conv_b[p0 + pp];
        #pragma unroll
        for (int i = 0; i < 16; i++) acc[pp][i] = bias;
    }

    int y = tid >> 2, x0 = (tid & 3) << 4;
    const float* xb = x + b * 3 * HWd;
    const float* cw = conv_w + p0 * 243;

    for (int c = 0; c < 3; c++) {
        __syncthreads();
        for (int i = tid; i < HWd; i += 256) {
            int yy = i >> 6, xx = i & 63;
            xpad[yy + 4][xx + 4] = xb[c * HWd + i];
        }
        __syncthreads();
        #pragma unroll 1
        for (int dy = 0; dy < 9; dy++) {
            float r[24];
            #pragma unroll
            for (int t = 0; t < 24; t++) r[t] = xpad[y + dy][x0 + t];
            #pragma unroll
            for (int dx = 0; dx < 9; dx++) {
                int widx = c * 81 + dy * 9 + dx;
                #pragma unroll
                for (int pp = 0; pp < 4; pp++) {
                    float wv = cw[pp * 243 + widx];   // uniform -> s_load
                    #pragma unroll
                    for (int i = 0; i < 16; i++)
                        acc[pp][i] = fmaf(r[i + dx], wv, acc[pp][i]);
                }
            }
        }
    }

    #pragma unroll
    for (int pp = 0; pp < 4; pp++) {
        size_t base = ((size_t)(b * 256 + p0 + pp)) * HWd + y * Wd + x0;
        u16 hb[16], lb[16];
        #pragma unroll
        for (int i = 0; i < 16; i++) {
            float val = fmaxf(acc[pp][i], 0.f);
            u16 h = f2bf(val);
            hb[i] = h;
            lb[i] = f2bf(val - bf2f(h));
        }
        *(uint4*)(feat_hi + base)     = *(uint4*)(hb);
        *(uint4*)(feat_hi + base + 8) = *(uint4*)(hb + 8);
        *(uint4*)(feat_lo + base)     = *(uint4*)(lb);
        *(uint4*)(feat_lo + base + 8) = *(uint4*)(lb + 8);
    }
}

// ---------------------------------------------------------------------------
// K2: bf16x3 MFMA GEMM with register prefetch of the next K-tile (global
// latency overlapped with MFMA).  C = A@B + bias; B pre-transposed [N][K].
// 64x64 tile, BK=64, 4 waves.  mode 0: Co fp32.  mode 1: Ch/Cl bf16 hi/lo.
// ---------------------------------------------------------------------------
__global__ __launch_bounds__(256, 4) void gemm_mfma3(
    const u16* __restrict__ Ah, const u16* __restrict__ Al,
    const u16* __restrict__ Bh, const u16* __restrict__ Bl,
    const float* __restrict__ bias,
    float* __restrict__ Co, u16* __restrict__ Ch, u16* __restrict__ Cl,
    int N, int K, int mode) {
    __shared__ u16 sAh[64 * 72], sAl[64 * 72], sBh[64 * 72], sBl[64 * 72];
    int tid = threadIdx.x;
    int w = tid >> 6;
    int L = tid & 63;
    int m16 = L & 15, qd = L >> 4;
    int mb = blockIdx.y * 64, nb = blockIdx.x * 64;

    f32x4 acc[4];
    #pragma unroll
    for (int i = 0; i < 4; i++) acc[i] = (f32x4){0.f, 0.f, 0.f, 0.f};

    int r = tid >> 2, s = tid & 3;
    const u16* pAh = Ah + (size_t)(mb + r) * K + s * 16;
    const u16* pAl = Al + (size_t)(mb + r) * K + s * 16;
    const u16* pBh = Bh + (size_t)(nb + r) * K + s * 16;
    const u16* pBl = Bl + (size_t)(nb + r) * K + s * 16;
    u16* dAh = &sAh[r * 72 + s * 16];
    u16* dAl = &sAl[r * 72 + s * 16];
    u16* dBh = &sBh[r * 72 + s * 16];
    u16* dBl = &sBl[r * 72 + s * 16];

    uint4 a0 = *(const uint4*)(pAh);
    uint4 a1 = *(const uint4*)(pAh + 8);
    uint4 a2 = *(const uint4*)(pAl);
    uint4 a3 = *(const uint4*)(pAl + 8);
    uint4 b0 = *(const uint4*)(pBh);
    uint4 b1 = *(const uint4*)(pBh + 8);
    uint4 b2 = *(const uint4*)(pBl);
    uint4 b3 = *(const uint4*)(pBl + 8);

    for (int k0 = 0; k0 < K; k0 += 64) {
        __syncthreads();
        *(uint4*)(dAh) = a0; *(uint4*)(dAh + 8) = a1;
        *(uint4*)(dAl) = a2; *(uint4*)(dAl + 8) = a3;
        *(uint4*)(dBh) = b0; *(uint4*)(dBh + 8) = b1;
        *(uint4*)(dBl) = b2; *(uint4*)(dBl + 8) = b3;
        __syncthreads();
        int kn = k0 + 64;
        if (kn < K) {   // prefetch next tile; latency hidden under MFMA below
            a0 = *(const uint4*)(pAh + kn);
            a1 = *(const uint4*)(pAh + kn + 8);
            a2 = *(const uint4*)(pAl + kn);
            a3 = *(const uint4*)(pAl + kn + 8);
            b0 = *(const uint4*)(pBh + kn);
            b1 = *(const uint4*)(pBh + kn + 8);
            b2 = *(const uint4*)(pBl + kn);
            b3 = *(const uint4*)(pBl + kn + 8);
        }
        #pragma unroll
        for (int c = 0; c < 2; c++) {
            int ab = (w * 16 + m16) * 72 + c * 32 + qd * 8;
            short8 aH = *(const short8*)&sAh[ab];
            short8 aL = *(const short8*)&sAl[ab];
            #pragma unroll
            for (int ct = 0; ct < 4; ct++) {
                int bb = (ct * 16 + m16) * 72 + c * 32 + qd * 8;
                short8 bH = *(const short8*)&sBh[bb];
                short8 bL = *(const short8*)&sBl[bb];
                acc[ct] = __builtin_amdgcn_mfma_f32_16x16x32_bf16(aH, bH, acc[ct], 0, 0, 0);
                acc[ct] = __builtin_amdgcn_mfma_f32_16x16x32_bf16(aH, bL, acc[ct], 0, 0, 0);
                acc[ct] = __builtin_amdgcn_mfma_f32_16x16x32_bf16(aL, bH, acc[ct], 0, 0, 0);
            }
        }
    }

    #pragma unroll
    for (int ct = 0; ct < 4; ct++) {
        int gc = nb + ct * 16 + m16;
        float bv = bias[gc];
        #pragma unroll
        for (int i = 0; i < 4; i++) {
            int gr = mb + w * 16 + qd * 4 + i;
            float val = acc[ct][i] + bv;
            size_t oi = (size_t)gr * N + gc;
            if (mode == 0) {
                Co[oi] = val;
            } else {
                u16 h = f2bf(val);
                Ch[oi] = h;
                Cl[oi] = f2bf(val - bf2f(h));
            }
        }
    }
}

// ---------------------------------------------------------------------------
// K4: attention over fused qkv[4096][768] (q|k|v per row).
// ---------------------------------------------------------------------------
__global__ __launch_bounds__(256) void attention(
    const float* __restrict__ qkv, float* __restrict__ o) {
    __shared__ float ksh[128][32];
    __shared__ float vsh[128][32];
    int blk = blockIdx.x;          // b*8 + h
    int b = blk >> 3, h = blk & 7;
    int r = threadIdx.x;
    const float rs = 0.17677669529663687f;  // 1/sqrt(32)

    float qr[32];
    const float* qrow = qkv + ((size_t)(b * Pd + r)) * 768 + h * DHd;
    #pragma unroll
    for (int d = 0; d < 32; d++) qr[d] = qrow[d];

    float m = -1e30f, l = 0.f;
    float oacc[32];
    #pragma unroll
    for (int d = 0; d < 32; d++) oacc[d] = 0.f;

    for (int ch = 0; ch < 2; ch++) {
        __syncthreads();
        {
            int row = r >> 1, dh = (r & 1) << 4;
            const float* srck = qkv + ((size_t)(b * Pd + ch * 128 + row)) * 768 + 256 + h * DHd + dh;
            const float* srcv = srck + 256;
            #pragma unroll
            for (int i = 0; i < 16; i++) { ksh[row][dh + i] = srck[i]; vsh[row][dh + i] = srcv[i]; }
        }
        __syncthreads();
        for (int kk = 0; kk < 128; kk++) {
            float s = 0.f;
            #pragma unroll
            for (int d = 0; d < 32; d++) s = fmaf(qr[d], ksh[kk][d], s);
            s *= rs;
            float mnew = fmaxf(m, s);
            float scale = __expf(m - mnew);
            float pexp = __expf(s - mnew);
            l = l * scale + pexp;
            #pragma unroll
            for (int d = 0; d < 32; d++) oacc[d] = fmaf(oacc[d], scale, pexp * vsh[kk][d]);
            m = mnew;
        }
    }
    float rinv = 1.f / l;
    float* orow = o + ((size_t)(b * Pd + r)) * Ed + h * DHd;
    #pragma unroll
    for (int d = 0; d < 32; d++) orow[d] = oacc[d] * rinv;
}

// ---------------------------------------------------------------------------
// K5: fused head. One wave per (b,p): tp = tanh(o@M2 + h0); pos embed; patches.
// ---------------------------------------------------------------------------
#define PATCH_OUT 995328   // 16*256*243
__global__ __launch_bounds__(256) void head_kernel(
    const float* __restrict__ o, const float* __restrict__ M2,
    const float* __restrict__ h0, const float* __restrict__ pos_w,
    const float* __restrict__ pos_b, const float* __restrict__ x,
    float* __restrict__ out) {
    int w = threadIdx.x >> 6, lane = threadIdx.x & 63;
    int bp = blockIdx.x * 4 + w;
    int b = bp >> 8;

    const float* orow = o + (size_t)bp * Ed;
    float4 o4 = *(const float4*)(orow + lane * 4);
    int e0 = lane * 4;
    float s0 = o4.x * M2[2 * e0 + 0] + o4.y * M2[2 * e0 + 2] + o4.z * M2[2 * e0 + 4] + o4.w * M2[2 * e0 + 6];
    float s1 = o4.x * M2[2 * e0 + 1] + o4.y * M2[2 * e0 + 3] + o4.z * M2[2 * e0 + 5] + o4.w * M2[2 * e0 + 7];
    #pragma unroll
    for (int off = 32; off; off >>= 1) { s0 += __shfl_xor(s0, off); s1 += __shfl_xor(s1, off); }

    float tx = tanhf(s0 + h0[0]);
    float ty = tanhf(s1 + h0[1]);

    {
        float pv = tx * pos_w[lane] + ty * pos_w[64 + lane] + pos_b[lane];
        out[PATCH_OUT + bp * POSDd + lane] = pv;
    }

    const float* xb = x + b * 3 * HWd;
    #pragma unroll
    for (int s = 0; s < 4; s++) {
        int idx = s * 64 + lane;
        if (idx < 243) {
            int c = idx / 81;
            int rem = idx - c * 81;
            int iy = rem / 9;
            int jx = rem - iy * 9;
            float basex = (2.f * jx + 1.f) / 9.f - 1.f;
            float basey = (2.f * iy + 1.f) / 9.f - 1.f;
            float gx = 0.140625f * basex + tx;
            float gy = 0.140625f * basey + ty;
            float ix  = ((gx + 1.f) * 64.f - 1.f) * 0.5f;
            float iyf = ((gy + 1.f) * 64.f - 1.f) * 0.5f;
            float x0f = floorf(ix), y0f = floorf(iyf);
            float wx = ix - x0f, wy = iyf - y0f;
            int x0i = min(max((int)x0f, 0), 63);
            int x1i = min(max((int)x0f + 1, 0), 63);
            int y0i = min(max((int)y0f, 0), 63);
            int y1i = min(max((int)y0f + 1, 0), 63);
            const float* xc = xb + c * HWd;
            float v00 = xc[y0i * Wd + x0i];
            float v01 = xc[y0i * Wd + x1i];
            float v10 = xc[y1i * Wd + x0i];
            float v11 = xc[y1i * Wd + x1i];
            float val = v00 * (1.f - wx) * (1.f - wy) + v01 * wx * (1.f - wy)
                      + v10 * (1.f - wx) * wy + v11 * wx * wy;
            out[bp * 243 + idx] = val;
        }
    }
}

// ---------------------------------------------------------------------------
extern "C" void kernel_launch(void* const* d_in, const int* in_sizes, int n_in,
                              void* d_out, int out_size, void* d_ws, size_t ws_size,
                              hipStream_t stream) {
    (void)in_sizes; (void)n_in; (void)out_size;
    const float* x      = (const float*)d_in[0];
    const float* conv_w = (const float*)d_in[1];
    const float* conv_b = (const float*)d_in[2];
    const float* in_w   = (const float*)d_in[3];
    const float* in_b   = (const float*)d_in[4];
    const float* wq     = (const float*)d_in[5];
    const float* bq     = (const float*)d_in[6];
    const float* wk     = (const float*)d_in[7];
    const float* bk     = (const float*)d_in[8];
    const float* wv     = (const float*)d_in[9];
    const float* bv     = (const float*)d_in[10];
    const float* wo     = (const float*)d_in[11];
    const float* bo     = (const float*)d_in[12];
    const float* out_w  = (const float*)d_in[13];
    const float* out_b  = (const float*)d_in[14];
    const float* fc_w   = (const float*)d_in[15];
    const float* fc_b   = (const float*)d_in[16];
    const float* pos_w  = (const float*)d_in[17];
    const float* pos_b  = (const float*)d_in[18];

    // ws budget (u16): feat 2*CB*1M, tok 2*1M, inw_t 2*1M, wqkv_t 2*196608.
    // fp32: bqkv 768, qkv 3M, o 1M, G/M2/h0 ~1K.
    int CB = 16;
    for (;;) {
        size_t need = ((size_t)(2 * CB + 4) * 1048576 + 2 * 196608) * 2
                    + (768 + 3145728 + 1048576 + 2048) * 4;
        if (need <= ws_size || CB == 1) break;
        CB >>= 1;
    }
    int nchunks = 16 / CB;

    char* base = (char*)d_ws;
    u16* feat_hi = (u16*)base;
    u16* feat_lo = feat_hi + (size_t)CB * 1048576;
    u16* tok_hi  = feat_lo + (size_t)CB * 1048576;
    u16* tok_lo  = tok_hi + 1048576;
    u16* inw_h   = tok_lo + 1048576;
    u16* inw_l   = inw_h + 1048576;
    u16* wqkv_h  = inw_l + 1048576;
    u16* wqkv_l  = wqkv_h + 196608;
    float* bqkv  = (float*)(wqkv_l + 196608);
    float* qkv   = bqkv + 768;
    float* o     = qkv + 3145728;
    float* G     = o + 1048576;
    float* M2    = G + 512;
    float* h0    = M2 + 512;
    float* out   = (float*)d_out;

    hipLaunchKernelGGL(precompute_G, dim3(258), dim3(64), 0, stream,
                       out_w, fc_w, out_b, fc_b, G, h0);
    hipLaunchKernelGGL(precompute_M2, dim3(258), dim3(64), 0, stream,
                       wo, bo, G, M2, h0);
    hipLaunchKernelGGL(prep_weight_t, dim3(64, 4), dim3(256), 0, stream,
                       in_w, inw_h, inw_l, 4096, 256);
    hipLaunchKernelGGL(prep_weight_t, dim3(4, 4), dim3(256), 0, stream,
                       wq, wqkv_h, wqkv_l, 256, 256);
    hipLaunchKernelGGL(prep_weight_t, dim3(4, 4), dim3(256), 0, stream,
                       wk, wqkv_h + 256 * 256, wqkv_l + 256 * 256, 256, 256);
    hipLaunchKernelGGL(prep_weight_t, dim3(4, 4), dim3(256), 0, stream,
                       wv, wqkv_h + 512 * 256, wqkv_l + 512 * 256, 256, 256);
    hipLaunchKernelGGL(concat_bias, dim3(1), dim3(256), 0, stream,
                       bq, bk, bv, bqkv);

    for (int c = 0; c < nchunks; ++c) {
        hipLaunchKernelGGL(conv_relu, dim3(CB * 64), dim3(256), 0, stream,
                           x + (size_t)c * CB * 3 * HWd, conv_w, conv_b,
                           feat_hi, feat_lo);
        hipLaunchKernelGGL(gemm_mfma3, dim3(4, CB * 4), dim3(256), 0, stream,
                           feat_hi, feat_lo, inw_h, inw_l, in_b,
                           (float*)nullptr,
                           tok_hi + (size_t)c * CB * 65536,
                           tok_lo + (size_t)c * CB * 65536,
                           256, 4096, 1);
    }
    // fused q|k|v GEMM: C[4096][768]
    hipLaunchKernelGGL(gemm_mfma3, dim3(12, 64), dim3(256), 0, stream,
                       tok_hi, tok_lo, wqkv_h, wqkv_l, bqkv,
                       qkv, (u16*)nullptr, (u16*)nullptr, 768, 256, 0);
    hipLaunchKernelGGL(attention, dim3(128), dim3(256), 0, stream, qkv, o);
    hipLaunchKernelGGL(head_kernel, dim3(1024), dim3(256), 0, stream,
                       o, M2, h0, pos_w, pos_b, x, out);
}

// Round 7
// 346.356 us; speedup vs baseline: 2.3481x; 1.2592x over previous
//
#include <hip/hip_runtime.h>
#include <hip/hip_bf16.h>

// Problem dims
#define Bd 16
#define Cd 3
#define Hd 64
#define Wd 64
#define Pd 256
#define PSd 9
#define Ed 256
#define NHd 8
#define DHd 32
#define HWd 4096
#define POSDd 64

typedef unsigned short u16;
typedef short short8 __attribute__((ext_vector_type(8)));
typedef float f32x4 __attribute__((ext_vector_type(4)));

__device__ __forceinline__ float bf2f(u16 u) {
    union { unsigned int i; float f; } c; c.i = ((unsigned int)u) << 16; return c.f;
}
__device__ __forceinline__ u16 f2bf(float f) {
    unsigned int x = __float_as_uint(f);
    unsigned int r = (x + 0x7fffu + ((x >> 16) & 1u)) >> 16;
    return (u16)r;
}

// ---------------------------------------------------------------------------
// K0a: G[e][j] = sum_hw out_w[e,hw] * fc_w[hw,j]   (e<256, j<2)
//      blocks 256,257: h0[j] = sum_hw out_b[hw]*fc_w[hw,j] + fc_b[j]
// ---------------------------------------------------------------------------
__global__ __launch_bounds__(64) void precompute_G(
    const float* __restrict__ out_w, const float* __restrict__ fc_w,
    const float* __restrict__ out_b, const float* __restrict__ fc_b,
    float* __restrict__ G, float* __restrict__ h0) {
    int blk = blockIdx.x, lane = threadIdx.x;
    if (blk < 256) {
        int e = blk;
        float a0 = 0.f, a1 = 0.f;
        for (int i = lane; i < HWd; i += 64) {
            float a = out_w[e * HWd + i];
            a0 += a * fc_w[2 * i];
            a1 += a * fc_w[2 * i + 1];
        }
        #pragma unroll
        for (int off = 32; off; off >>= 1) { a0 += __shfl_xor(a0, off); a1 += __shfl_xor(a1, off); }
        if (lane == 0) { G[2 * e] = a0; G[2 * e + 1] = a1; }
    } else {
        int j = blk - 256;
        float a = 0.f;
        for (int i = lane; i < HWd; i += 64) a += out_b[i] * fc_w[2 * i + j];
        #pragma unroll
        for (int off = 32; off; off >>= 1) a += __shfl_xor(a, off);
        if (lane == 0) h0[j] = a + fc_b[j];
    }
}

// ---------------------------------------------------------------------------
// K0b (parallel): block e<256: M2[e][:] = sum_f wo[e,f]*G[f][:]
//                 blocks 256,257: h0[j] += sum_e bo[e]*G[e][j]
// ---------------------------------------------------------------------------
__global__ __launch_bounds__(64) void precompute_M2(
    const float* __restrict__ wo, const float* __restrict__ bo,
    const float* __restrict__ G, float* __restrict__ M2, float* __restrict__ h0) {
    int blk = blockIdx.x, lane = threadIdx.x;
    if (blk < 256) {
        float m0 = 0.f, m1 = 0.f;
        for (int f = lane; f < Ed; f += 64) {
            float wv = wo[blk * Ed + f];
            m0 += wv * G[2 * f];
            m1 += wv * G[2 * f + 1];
        }
        #pragma unroll
        for (int off = 32; off; off >>= 1) { m0 += __shfl_xor(m0, off); m1 += __shfl_xor(m1, off); }
        if (lane == 0) { M2[2 * blk] = m0; M2[2 * blk + 1] = m1; }
    } else {
        int j = blk - 256;
        float hh = 0.f;
        for (int f = lane; f < Ed; f += 64) hh += bo[f] * G[2 * f + j];
        #pragma unroll
        for (int off = 32; off; off >>= 1) hh += __shfl_xor(hh, off);
        if (lane == 0) h0[j] += hh;
    }
}

// ---------------------------------------------------------------------------
// prep: W[K][N] fp32 -> Th/Tl[N][K] bf16 hi/lo, LDS-tiled transpose.
// ---------------------------------------------------------------------------
__global__ __launch_bounds__(256) void prep_weight_t(
    const float* __restrict__ W, u16* __restrict__ Th, u16* __restrict__ Tl,
    int K, int N) {
    __shared__ u16 th[64][65];
    __shared__ u16 tl[64][65];
    int k0 = blockIdx.x * 64, n0 = blockIdx.y * 64;
    int col = threadIdx.x & 63, r4 = threadIdx.x >> 6;
    #pragma unroll
    for (int i = 0; i < 16; i++) {
        int kr = 4 * i + r4;
        float v = W[(size_t)(k0 + kr) * N + n0 + col];
        u16 h = f2bf(v);
        th[col][kr] = h;
        tl[col][kr] = f2bf(v - bf2f(h));
    }
    __syncthreads();
    #pragma unroll
    for (int i = 0; i < 16; i++) {
        int nr = 4 * i + r4;
        Th[(size_t)(n0 + nr) * K + k0 + col] = th[nr][col];
        Tl[(size_t)(n0 + nr) * K + k0 + col] = tl[nr][col];
    }
}

// concat bq,bk,bv -> b3[768]
__global__ __launch_bounds__(256) void concat_bias(
    const float* __restrict__ bq, const float* __restrict__ bk,
    const float* __restrict__ bv, float* __restrict__ b3) {
    int t = threadIdx.x;
    b3[t] = bq[t]; b3[256 + t] = bk[t]; b3[512 + t] = bv[t];
}

// ---------------------------------------------------------------------------
// K1: conv 9x9 pad4 + bias + relu -> feat bf16 hi/lo [bp][hw].
// 4 output channels per block; one input channel staged at a time.
// ---------------------------------------------------------------------------
__global__ __launch_bounds__(256, 4) void conv_relu(
    const float* __restrict__ x, const float* __restrict__ conv_w,
    const float* __restrict__ conv_b,
    u16* __restrict__ feat_hi, u16* __restrict__ feat_lo) {
    __shared__ float xpad[72][73];
    int blk = blockIdx.x;
    int b = blk >> 6, p0 = (blk & 63) << 2;
    int tid = threadIdx.x;

    float* xf = &xpad[0][0];
    for (int i = tid; i < 72 * 73; i += 256) xf[i] = 0.f;

    float acc[4][16];
    #pragma unroll
    for (int pp = 0; pp < 4; pp++) {
        float bias = conv_b[p0 + pp];
        #pragma unroll
        for (int i = 0; i < 16; i++) acc[pp][i] = bias;
    }

    int y = tid >> 2, x0 = (tid & 3) << 4;
    const float* xb = x + b * 3 * HWd;
    const float* cw = conv_w + p0 * 243;

    for (int c = 0; c < 3; c++) {
        __syncthreads();
        for (int i = tid; i < HWd; i += 256) {
            int yy = i >> 6, xx = i & 63;
            xpad[yy + 4][xx + 4] = xb[c * HWd + i];
        }
        __syncthreads();
        #pragma unroll 1
        for (int dy = 0; dy < 9; dy++) {
            float r[24];
            #pragma unroll
            for (int t = 0; t < 24; t++) r[t] = xpad[y + dy][x0 + t];
            #pragma unroll
            for (int dx = 0; dx < 9; dx++) {
                int widx = c * 81 + dy * 9 + dx;
                #pragma unroll
                for (int pp = 0; pp < 4; pp++) {
                    float wv = cw[pp * 243 + widx];   // uniform -> s_load
                    #pragma unroll
                    for (int i = 0; i < 16; i++)
                        acc[pp][i] = fmaf(r[i + dx], wv, acc[pp][i]);
                }
            }
        }
    }

    #pragma unroll
    for (int pp = 0; pp < 4; pp++) {
        size_t base = ((size_t)(b * 256 + p0 + pp)) * HWd + y * Wd + x0;
        u16 hb[16], lb[16];
        #pragma unroll
        for (int i = 0; i < 16; i++) {
            float val = fmaxf(acc[pp][i], 0.f);
            u16 h = f2bf(val);
            hb[i] = h;
            lb[i] = f2bf(val - bf2f(h));
        }
        *(uint4*)(feat_hi + base)     = *(uint4*)(hb);
        *(uint4*)(feat_hi + base + 8) = *(uint4*)(hb + 8);
        *(uint4*)(feat_lo + base)     = *(uint4*)(lb);
        *(uint4*)(feat_lo + base + 8) = *(uint4*)(lb + 8);
    }
}

// ---------------------------------------------------------------------------
// K2: bf16x3 MFMA GEMM with register prefetch of the next K-tile.
// ---------------------------------------------------------------------------
__global__ __launch_bounds__(256, 4) void gemm_mfma3(
    const u16* __restrict__ Ah, const u16* __restrict__ Al,
    const u16* __restrict__ Bh, const u16* __restrict__ Bl,
    const float* __restrict__ bias,
    float* __restrict__ Co, u16* __restrict__ Ch, u16* __restrict__ Cl,
    int N, int K, int mode) {
    __shared__ u16 sAh[64 * 72], sAl[64 * 72], sBh[64 * 72], sBl[64 * 72];
    int tid = threadIdx.x;
    int w = tid >> 6;
    int L = tid & 63;
    int m16 = L & 15, qd = L >> 4;
    int mb = blockIdx.y * 64, nb = blockIdx.x * 64;

    f32x4 acc[4];
    #pragma unroll
    for (int i = 0; i < 4; i++) acc[i] = (f32x4){0.f, 0.f, 0.f, 0.f};

    int r = tid >> 2, s = tid & 3;
    const u16* pAh = Ah + (size_t)(mb + r) * K + s * 16;
    const u16* pAl = Al + (size_t)(mb + r) * K + s * 16;
    const u16* pBh = Bh + (size_t)(nb + r) * K + s * 16;
    const u16* pBl = Bl + (size_t)(nb + r) * K + s * 16;
    u16* dAh = &sAh[r * 72 + s * 16];
    u16* dAl = &sAl[r * 72 + s * 16];
    u16* dBh = &sBh[r * 72 + s * 16];
    u16* dBl = &sBl[r * 72 + s * 16];

    uint4 a0 = *(const uint4*)(pAh);
    uint4 a1 = *(const uint4*)(pAh + 8);
    uint4 a2 = *(const uint4*)(pAl);
    uint4 a3 = *(const uint4*)(pAl + 8);
    uint4 b0 = *(const uint4*)(pBh);
    uint4 b1 = *(const uint4*)(pBh + 8);
    uint4 b2 = *(const uint4*)(pBl);
    uint4 b3 = *(const uint4*)(pBl + 8);

    for (int k0 = 0; k0 < K; k0 += 64) {
        __syncthreads();
        *(uint4*)(dAh) = a0; *(uint4*)(dAh + 8) = a1;
        *(uint4*)(dAl) = a2; *(uint4*)(dAl + 8) = a3;
        *(uint4*)(dBh) = b0; *(uint4*)(dBh + 8) = b1;
        *(uint4*)(dBl) = b2; *(uint4*)(dBl + 8) = b3;
        __syncthreads();
        int kn = k0 + 64;
        if (kn < K) {   // prefetch next tile; latency hidden under MFMA below
            a0 = *(const uint4*)(pAh + kn);
            a1 = *(const uint4*)(pAh + kn + 8);
            a2 = *(const uint4*)(pAl + kn);
            a3 = *(const uint4*)(pAl + kn + 8);
            b0 = *(const uint4*)(pBh + kn);
            b1 = *(const uint4*)(pBh + kn + 8);
            b2 = *(const uint4*)(pBl + kn);
            b3 = *(const uint4*)(pBl + kn + 8);
        }
        #pragma unroll
        for (int c = 0; c < 2; c++) {
            int ab = (w * 16 + m16) * 72 + c * 32 + qd * 8;
            short8 aH = *(const short8*)&sAh[ab];
            short8 aL = *(const short8*)&sAl[ab];
            #pragma unroll
            for (int ct = 0; ct < 4; ct++) {
                int bb = (ct * 16 + m16) * 72 + c * 32 + qd * 8;
                short8 bH = *(const short8*)&sBh[bb];
                short8 bL = *(const short8*)&sBl[bb];
                acc[ct] = __builtin_amdgcn_mfma_f32_16x16x32_bf16(aH, bH, acc[ct], 0, 0, 0);
                acc[ct] = __builtin_amdgcn_mfma_f32_16x16x32_bf16(aH, bL, acc[ct], 0, 0, 0);
                acc[ct] = __builtin_amdgcn_mfma_f32_16x16x32_bf16(aL, bH, acc[ct], 0, 0, 0);
            }
        }
    }

    #pragma unroll
    for (int ct = 0; ct < 4; ct++) {
        int gc = nb + ct * 16 + m16;
        float bv = bias[gc];
        #pragma unroll
        for (int i = 0; i < 4; i++) {
            int gr = mb + w * 16 + qd * 4 + i;
            float val = acc[ct][i] + bv;
            size_t oi = (size_t)gr * N + gc;
            if (mode == 0) {
                Co[oi] = val;
            } else {
                u16 h = f2bf(val);
                Ch[oi] = h;
                Cl[oi] = f2bf(val - bf2f(h));
            }
        }
    }
}

// ---------------------------------------------------------------------------
// K4: attention over fused qkv[4096][768] (q|k|v per row).
// grid (b, h, qc): 512 blocks.  Thread t: q-row = qc*64 + (t>>2), owns 8 of
// the 32 dims (sub = t&3).  Dot product closed by shfl_xor(1),(2) within the
// 4-lane row group.  K/V staged 64 rows at a time; reads are broadcasts.
// ---------------------------------------------------------------------------
__global__ __launch_bounds__(256) void attention(
    const float* __restrict__ qkv, float* __restrict__ o) {
    __shared__ float ksh[64][32];
    __shared__ float vsh[64][32];
    int b = blockIdx.x, h = blockIdx.y, qc = blockIdx.z;
    int t = threadIdx.x;
    int row = t >> 2, sub = t & 3;
    int r = qc * 64 + row;
    const float rs = 0.17677669529663687f;  // 1/sqrt(32)

    float qr[8];
    const float* qrow = qkv + ((size_t)(b * Pd + r)) * 768 + h * DHd + sub * 8;
    #pragma unroll
    for (int d = 0; d < 8; d++) qr[d] = qrow[d];

    float m = -1e30f, l = 0.f;
    float oacc[8];
    #pragma unroll
    for (int d = 0; d < 8; d++) oacc[d] = 0.f;

    for (int ch = 0; ch < 4; ch++) {
        __syncthreads();
        {
            const float* srck = qkv + ((size_t)(b * Pd + ch * 64 + row)) * 768 + 256 + h * DHd + sub * 8;
            const float* srcv = srck + 256;
            float4 k0 = *(const float4*)(srck);
            float4 k1 = *(const float4*)(srck + 4);
            float4 v0 = *(const float4*)(srcv);
            float4 v1 = *(const float4*)(srcv + 4);
            *(float4*)&ksh[row][sub * 8]     = k0;
            *(float4*)&ksh[row][sub * 8 + 4] = k1;
            *(float4*)&vsh[row][sub * 8]     = v0;
            *(float4*)&vsh[row][sub * 8 + 4] = v1;
        }
        __syncthreads();
        #pragma unroll 2
        for (int kk = 0; kk < 64; kk++) {
            float4 ka = *(const float4*)&ksh[kk][sub * 8];
            float4 kb = *(const float4*)&ksh[kk][sub * 8 + 4];
            float s0 = qr[0] * ka.x + qr[1] * ka.y;
            float s1 = qr[2] * ka.z + qr[3] * ka.w;
            float s2 = qr[4] * kb.x + qr[5] * kb.y;
            float s3 = qr[6] * kb.z + qr[7] * kb.w;
            float s = (s0 + s1) + (s2 + s3);
            s += __shfl_xor(s, 1);
            s += __shfl_xor(s, 2);
            s *= rs;
            float mnew = fmaxf(m, s);
            float scale = __expf(m - mnew);
            float pexp = __expf(s - mnew);
            l = l * scale + pexp;
            float4 va = *(const float4*)&vsh[kk][sub * 8];
            float4 vb = *(const float4*)&vsh[kk][sub * 8 + 4];
            oacc[0] = fmaf(oacc[0], scale, pexp * va.x);
            oacc[1] = fmaf(oacc[1], scale, pexp * va.y);
            oacc[2] = fmaf(oacc[2], scale, pexp * va.z);
            oacc[3] = fmaf(oacc[3], scale, pexp * va.w);
            oacc[4] = fmaf(oacc[4], scale, pexp * vb.x);
            oacc[5] = fmaf(oacc[5], scale, pexp * vb.y);
            oacc[6] = fmaf(oacc[6], scale, pexp * vb.z);
            oacc[7] = fmaf(oacc[7], scale, pexp * vb.w);
            m = mnew;
        }
    }
    float rinv = 1.f / l;
    float* orow = o + ((size_t)(b * Pd + r)) * Ed + h * DHd + sub * 8;
    #pragma unroll
    for (int d = 0; d < 8; d++) orow[d] = oacc[d] * rinv;
}

// ---------------------------------------------------------------------------
// K5: fused head. One wave per (b,p): tp = tanh(o@M2 + h0); pos embed; patches.
// ---------------------------------------------------------------------------
#define PATCH_OUT 995328   // 16*256*243
__global__ __launch_bounds__(256) void head_kernel(
    const float* __restrict__ o, const float* __restrict__ M2,
    const float* __restrict__ h0, const float* __restrict__ pos_w,
    const float* __restrict__ pos_b, const float* __restrict__ x,
    float* __restrict__ out) {
    int w = threadIdx.x >> 6, lane = threadIdx.x & 63;
    int bp = blockIdx.x * 4 + w;
    int b = bp >> 8;

    const float* orow = o + (size_t)bp * Ed;
    float4 o4 = *(const float4*)(orow + lane * 4);
    int e0 = lane * 4;
    float s0 = o4.x * M2[2 * e0 + 0] + o4.y * M2[2 * e0 + 2] + o4.z * M2[2 * e0 + 4] + o4.w * M2[2 * e0 + 6];
    float s1 = o4.x * M2[2 * e0 + 1] + o4.y * M2[2 * e0 + 3] + o4.z * M2[2 * e0 + 5] + o4.w * M2[2 * e0 + 7];
    #pragma unroll
    for (int off = 32; off; off >>= 1) { s0 += __shfl_xor(s0, off); s1 += __shfl_xor(s1, off); }

    float tx = tanhf(s0 + h0[0]);
    float ty = tanhf(s1 + h0[1]);

    {
        float pv = tx * pos_w[lane] + ty * pos_w[64 + lane] + pos_b[lane];
        out[PATCH_OUT + bp * POSDd + lane] = pv;
    }

    const float* xb = x + b * 3 * HWd;
    #pragma unroll
    for (int s = 0; s < 4; s++) {
        int idx = s * 64 + lane;
        if (idx < 243) {
            int c = idx / 81;
            int rem = idx - c * 81;
            int iy = rem / 9;
            int jx = rem - iy * 9;
            float basex = (2.f * jx + 1.f) / 9.f - 1.f;
            float basey = (2.f * iy + 1.f) / 9.f - 1.f;
            float gx = 0.140625f * basex + tx;
            float gy = 0.140625f * basey + ty;
            float ix  = ((gx + 1.f) * 64.f - 1.f) * 0.5f;
            float iyf = ((gy + 1.f) * 64.f - 1.f) * 0.5f;
            float x0f = floorf(ix), y0f = floorf(iyf);
            float wx = ix - x0f, wy = iyf - y0f;
            int x0i = min(max((int)x0f, 0), 63);
            int x1i = min(max((int)x0f + 1, 0), 63);
            int y0i = min(max((int)y0f, 0), 63);
            int y1i = min(max((int)y0f + 1, 0), 63);
            const float* xc = xb + c * HWd;
            float v00 = xc[y0i * Wd + x0i];
            float v01 = xc[y0i * Wd + x1i];
            float v10 = xc[y1i * Wd + x0i];
            float v11 = xc[y1i * Wd + x1i];
            float val = v00 * (1.f - wx) * (1.f - wy) + v01 * wx * (1.f - wy)
                      + v10 * (1.f - wx) * wy + v11 * wx * wy;
            out[bp * 243 + idx] = val;
        }
    }
}

// ---------------------------------------------------------------------------
extern "C" void kernel_launch(void* const* d_in, const int* in_sizes, int n_in,
                              void* d_out, int out_size, void* d_ws, size_t ws_size,
                              hipStream_t stream) {
    (void)in_sizes; (void)n_in; (void)out_size;
    const float* x      = (const float*)d_in[0];
    const float* conv_w = (const float*)d_in[1];
    const float* conv_b = (const float*)d_in[2];
    const float* in_w   = (const float*)d_in[3];
    const float* in_b   = (const float*)d_in[4];
    const float* wq     = (const float*)d_in[5];
    const float* bq     = (const float*)d_in[6];
    const float* wk     = (const float*)d_in[7];
    const float* bk     = (const float*)d_in[8];
    const float* wv     = (const float*)d_in[9];
    const float* bv     = (const float*)d_in[10];
    const float* wo     = (const float*)d_in[11];
    const float* bo     = (const float*)d_in[12];
    const float* out_w  = (const float*)d_in[13];
    const float* out_b  = (const float*)d_in[14];
    const float* fc_w   = (const float*)d_in[15];
    const float* fc_b   = (const float*)d_in[16];
    const float* pos_w  = (const float*)d_in[17];
    const float* pos_b  = (const float*)d_in[18];

    // ws budget (u16): feat 2*CB*1M, tok 2*1M, inw_t 2*1M, wqkv_t 2*196608.
    // fp32: bqkv 768, qkv 3M, o 1M, G/M2/h0 ~1K.
    int CB = 16;
    for (;;) {
        size_t need = ((size_t)(2 * CB + 4) * 1048576 + 2 * 196608) * 2
                    + (768 + 3145728 + 1048576 + 2048) * 4;
        if (need <= ws_size || CB == 1) break;
        CB >>= 1;
    }
    int nchunks = 16 / CB;

    char* base = (char*)d_ws;
    u16* feat_hi = (u16*)base;
    u16* feat_lo = feat_hi + (size_t)CB * 1048576;
    u16* tok_hi  = feat_lo + (size_t)CB * 1048576;
    u16* tok_lo  = tok_hi + 1048576;
    u16* inw_h   = tok_lo + 1048576;
    u16* inw_l   = inw_h + 1048576;
    u16* wqkv_h  = inw_l + 1048576;
    u16* wqkv_l  = wqkv_h + 196608;
    float* bqkv  = (float*)(wqkv_l + 196608);
    float* qkv   = bqkv + 768;
    float* o     = qkv + 3145728;
    float* G     = o + 1048576;
    float* M2    = G + 512;
    float* h0    = M2 + 512;
    float* out   = (float*)d_out;

    hipLaunchKernelGGL(precompute_G, dim3(258), dim3(64), 0, stream,
                       out_w, fc_w, out_b, fc_b, G, h0);
    hipLaunchKernelGGL(precompute_M2, dim3(258), dim3(64), 0, stream,
                       wo, bo, G, M2, h0);
    hipLaunchKernelGGL(prep_weight_t, dim3(64, 4), dim3(256), 0, stream,
                       in_w, inw_h, inw_l, 4096, 256);
    hipLaunchKernelGGL(prep_weight_t, dim3(4, 4), dim3(256), 0, stream,
                       wq, wqkv_h, wqkv_l, 256, 256);
    hipLaunchKernelGGL(prep_weight_t, dim3(4, 4), dim3(256), 0, stream,
                       wk, wqkv_h + 256 * 256, wqkv_l + 256 * 256, 256, 256);
    hipLaunchKernelGGL(prep_weight_t, dim3(4, 4), dim3(256), 0, stream,
                       wv, wqkv_h + 512 * 256, wqkv_l + 512 * 256, 256, 256);
    hipLaunchKernelGGL(concat_bias, dim3(1), dim3(256), 0, stream,
                       bq, bk, bv, bqkv);

    for (int c = 0; c < nchunks; ++c) {
        hipLaunchKernelGGL(conv_relu, dim3(CB * 64), dim3(256), 0, stream,
                           x + (size_t)c * CB * 3 * HWd, conv_w, conv_b,
                           feat_hi, feat_lo);
        hipLaunchKernelGGL(gemm_mfma3, dim3(4, CB * 4), dim3(256), 0, stream,
                           feat_hi, feat_lo, inw_h, inw_l, in_b,
                           (float*)nullptr,
                           tok_hi + (size_t)c * CB * 65536,
                           tok_lo + (size_t)c * CB * 65536,
                           256, 4096, 1);
    }
    // fused q|k|v GEMM: C[4096][768]
    hipLaunchKernelGGL(gemm_mfma3, dim3(12, 64), dim3(256), 0, stream,
                       tok_hi, tok_lo, wqkv_h, wqkv_l, bqkv,
                       qkv, (u16*)nullptr, (u16*)nullptr, 768, 256, 0);
    hipLaunchKernelGGL(attention, dim3(16, 8, 4), dim3(256), 0, stream, qkv, o);
    hipLaunchKernelGGL(head_kernel, dim3(1024), dim3(256), 0, stream,
                       o, M2, h0, pos_w, pos_b, x, out);
}

// Round 8
// 336.533 us; speedup vs baseline: 2.4167x; 1.0292x over previous
//
#include <hip/hip_runtime.h>
#include <hip/hip_bf16.h>

// Problem dims
#define Bd 16
#define Cd 3
#define Hd 64
#define Wd 64
#define Pd 256
#define PSd 9
#define Ed 256
#define NHd 8
#define DHd 32
#define HWd 4096
#define POSDd 64

typedef unsigned short u16;
typedef short short8 __attribute__((ext_vector_type(8)));
typedef float f32x4 __attribute__((ext_vector_type(4)));

__device__ __forceinline__ float bf2f(u16 u) {
    union { unsigned int i; float f; } c; c.i = ((unsigned int)u) << 16; return c.f;
}
__device__ __forceinline__ u16 f2bf(float f) {
    unsigned int x = __float_as_uint(f);
    unsigned int r = (x + 0x7fffu + ((x >> 16) & 1u)) >> 16;
    return (u16)r;
}

// ---------------------------------------------------------------------------
// K0a: G[e][j] = sum_hw out_w[e,hw] * fc_w[hw,j]   (e<256, j<2)
//      blocks 256,257: h0[j] = sum_hw out_b[hw]*fc_w[hw,j] + fc_b[j]
// ---------------------------------------------------------------------------
__global__ __launch_bounds__(64) void precompute_G(
    const float* __restrict__ out_w, const float* __restrict__ fc_w,
    const float* __restrict__ out_b, const float* __restrict__ fc_b,
    float* __restrict__ G, float* __restrict__ h0) {
    int blk = blockIdx.x, lane = threadIdx.x;
    if (blk < 256) {
        int e = blk;
        float a0 = 0.f, a1 = 0.f;
        for (int i = lane; i < HWd; i += 64) {
            float a = out_w[e * HWd + i];
            a0 += a * fc_w[2 * i];
            a1 += a * fc_w[2 * i + 1];
        }
        #pragma unroll
        for (int off = 32; off; off >>= 1) { a0 += __shfl_xor(a0, off); a1 += __shfl_xor(a1, off); }
        if (lane == 0) { G[2 * e] = a0; G[2 * e + 1] = a1; }
    } else {
        int j = blk - 256;
        float a = 0.f;
        for (int i = lane; i < HWd; i += 64) a += out_b[i] * fc_w[2 * i + j];
        #pragma unroll
        for (int off = 32; off; off >>= 1) a += __shfl_xor(a, off);
        if (lane == 0) h0[j] = a + fc_b[j];
    }
}

// ---------------------------------------------------------------------------
// K0b (parallel): block e<256: M2[e][:] = sum_f wo[e,f]*G[f][:]
//                 blocks 256,257: h0[j] += sum_e bo[e]*G[e][j]
// ---------------------------------------------------------------------------
__global__ __launch_bounds__(64) void precompute_M2(
    const float* __restrict__ wo, const float* __restrict__ bo,
    const float* __restrict__ G, float* __restrict__ M2, float* __restrict__ h0) {
    int blk = blockIdx.x, lane = threadIdx.x;
    if (blk < 256) {
        float m0 = 0.f, m1 = 0.f;
        for (int f = lane; f < Ed; f += 64) {
            float wv = wo[blk * Ed + f];
            m0 += wv * G[2 * f];
            m1 += wv * G[2 * f + 1];
        }
        #pragma unroll
        for (int off = 32; off; off >>= 1) { m0 += __shfl_xor(m0, off); m1 += __shfl_xor(m1, off); }
        if (lane == 0) { M2[2 * blk] = m0; M2[2 * blk + 1] = m1; }
    } else {
        int j = blk - 256;
        float hh = 0.f;
        for (int f = lane; f < Ed; f += 64) hh += bo[f] * G[2 * f + j];
        #pragma unroll
        for (int off = 32; off; off >>= 1) hh += __shfl_xor(hh, off);
        if (lane == 0) h0[j] += hh;
    }
}

// ---------------------------------------------------------------------------
// prep: W[K][N] fp32 -> Th/Tl[N][K] bf16 hi/lo, LDS-tiled transpose.
// ---------------------------------------------------------------------------
__global__ __launch_bounds__(256) void prep_weight_t(
    const float* __restrict__ W, u16* __restrict__ Th, u16* __restrict__ Tl,
    int K, int N) {
    __shared__ u16 th[64][65];
    __shared__ u16 tl[64][65];
    int k0 = blockIdx.x * 64, n0 = blockIdx.y * 64;
    int col = threadIdx.x & 63, r4 = threadIdx.x >> 6;
    #pragma unroll
    for (int i = 0; i < 16; i++) {
        int kr = 4 * i + r4;
        float v = W[(size_t)(k0 + kr) * N + n0 + col];
        u16 h = f2bf(v);
        th[col][kr] = h;
        tl[col][kr] = f2bf(v - bf2f(h));
    }
    __syncthreads();
    #pragma unroll
    for (int i = 0; i < 16; i++) {
        int nr = 4 * i + r4;
        Th[(size_t)(n0 + nr) * K + k0 + col] = th[nr][col];
        Tl[(size_t)(n0 + nr) * K + k0 + col] = tl[nr][col];
    }
}

// prep conv weights: conv_w[p][243] fp32 -> Ah/Al[p][256] bf16 hi/lo (K-pad 0)
__global__ __launch_bounds__(256) void prep_convw(
    const float* __restrict__ W, u16* __restrict__ Ah, u16* __restrict__ Al) {
    int p = blockIdx.x, k = threadIdx.x;
    float v = (k < 243) ? W[p * 243 + k] : 0.f;
    u16 h = f2bf(v);
    Ah[p * 256 + k] = h;
    Al[p * 256 + k] = f2bf(v - bf2f(h));
}

// concat bq,bk,bv -> b3[768]
__global__ __launch_bounds__(256) void concat_bias(
    const float* __restrict__ bq, const float* __restrict__ bk,
    const float* __restrict__ bv, float* __restrict__ b3) {
    int t = threadIdx.x;
    b3[t] = bq[t]; b3[256 + t] = bk[t]; b3[512 + t] = bv[t];
}

// ---------------------------------------------------------------------------
// K1: implicit-GEMM conv via MFMA (bf16x3).  feat[p][hw] = relu(W @ col + b).
// A = prepped conv weights [256 p][256 k] hi/lo.  B-tile [64 hw][64 k] built
// in-LDS each K-iter from a 3x9x72 fp32 row-window (one y-row per hw-tile),
// k decoded inline to (c,dy,dx) on the VALU pipe.  Fragment layout/addressing
// identical to gemm_mfma3 (proven correct).
// grid: (64 hw-tiles, 4 p-tiles, CB batches)
// ---------------------------------------------------------------------------
__global__ __launch_bounds__(256, 3) void conv_gemm(
    const u16* __restrict__ Ah, const u16* __restrict__ Al,
    const float* __restrict__ x, const float* __restrict__ conv_b,
    u16* __restrict__ feat_hi, u16* __restrict__ feat_lo) {
    __shared__ u16 sAh[64 * 72], sAl[64 * 72], sBh[64 * 72], sBl[64 * 72];
    __shared__ float wls[3 * 9 * 72];   // zero-padded row window
    int tid = threadIdx.x;
    int w = tid >> 6, L = tid & 63;
    int m16 = L & 15, qd = L >> 4;
    int nb = blockIdx.x * 64;           // hw tile == one image row
    int mb = blockIdx.y * 64;           // p tile
    int b  = blockIdx.z;                // batch (chunk-local)
    int y  = nb >> 6;

    // stage zero-padded window: rows y-4..y+4 (wr=0..8), cols -4..67 -> 0..71
    for (int i = tid; i < 3 * 9 * 72; i += 256) wls[i] = 0.f;
    __syncthreads();
    for (int i = tid; i < 3 * 9 * 64; i += 256) {
        int c = i / 576, rem = i - c * 576, wr = rem >> 6, col = rem & 63;
        int iy = y - 4 + wr;
        if (iy >= 0 && iy < 64)
            wls[c * 648 + wr * 72 + 4 + col] = x[((b * 3 + c) << 12) + (iy << 6) + col];
    }
    __syncthreads();

    f32x4 acc[4];
    #pragma unroll
    for (int i = 0; i < 4; i++) acc[i] = (f32x4){0.f, 0.f, 0.f, 0.f};

    int r = tid >> 2, s = tid & 3;      // A staging: row, k-quarter
    int n = r, kb = s * 16;             // B build: hw-col, 16-k strip
    const u16* pAh = Ah + (mb + r) * 256 + s * 16;
    const u16* pAl = Al + (mb + r) * 256 + s * 16;
    u16* dAh = &sAh[r * 72 + s * 16];
    u16* dAl = &sAl[r * 72 + s * 16];

    for (int k0 = 0; k0 < 256; k0 += 64) {
        uint4 a0 = *(const uint4*)(pAh + k0);
        uint4 a1 = *(const uint4*)(pAh + k0 + 8);
        uint4 a2 = *(const uint4*)(pAl + k0);
        uint4 a3 = *(const uint4*)(pAl + k0 + 8);
        // build this iter's 16-k strip of B in regs (reads wls only)
        u16 hbuf[16] __attribute__((aligned(8)));
        u16 lbuf[16] __attribute__((aligned(8)));
        #pragma unroll
        for (int j = 0; j < 16; j++) {
            int k = k0 + kb + j;
            float v = 0.f;
            if (k < 243) {
                int c = (k >= 81) + (k >= 162);
                int rem = k - c * 81;
                int dy = (rem * 57) >> 9;       // rem/9 for rem<81
                int dx = rem - dy * 9;
                v = wls[c * 648 + dy * 72 + dx + n];
            }
            u16 h = f2bf(v);
            hbuf[j] = h;
            lbuf[j] = f2bf(v - bf2f(h));
        }
        __syncthreads();
        *(uint4*)(dAh) = a0; *(uint4*)(dAh + 8) = a1;
        *(uint4*)(dAl) = a2; *(uint4*)(dAl + 8) = a3;
        #pragma unroll
        for (int t = 0; t < 4; t++) {
            *(ushort4*)&sBh[n * 72 + kb + 4 * t] = *(ushort4*)&hbuf[4 * t];
            *(ushort4*)&sBl[n * 72 + kb + 4 * t] = *(ushort4*)&lbuf[4 * t];
        }
        __syncthreads();
        #pragma unroll
        for (int c = 0; c < 2; c++) {
            int ab = (w * 16 + m16) * 72 + c * 32 + qd * 8;
            short8 aH = *(const short8*)&sAh[ab];
            short8 aL = *(const short8*)&sAl[ab];
            #pragma unroll
            for (int ct = 0; ct < 4; ct++) {
                int bb = (ct * 16 + m16) * 72 + c * 32 + qd * 8;
                short8 bH = *(const short8*)&sBh[bb];
                short8 bL = *(const short8*)&sBl[bb];
                acc[ct] = __builtin_amdgcn_mfma_f32_16x16x32_bf16(aH, bH, acc[ct], 0, 0, 0);
                acc[ct] = __builtin_amdgcn_mfma_f32_16x16x32_bf16(aH, bL, acc[ct], 0, 0, 0);
                acc[ct] = __builtin_amdgcn_mfma_f32_16x16x32_bf16(aL, bH, acc[ct], 0, 0, 0);
            }
        }
    }

    // epilogue: row bias + relu + hi/lo split -> feat[(b*256+p)][hw]
    float bias_i[4];
    #pragma unroll
    for (int i = 0; i < 4; i++) bias_i[i] = conv_b[mb + w * 16 + qd * 4 + i];
    #pragma unroll
    for (int ct = 0; ct < 4; ct++) {
        int gc = nb + ct * 16 + m16;
        #pragma unroll
        for (int i = 0; i < 4; i++) {
            int gr = mb + w * 16 + qd * 4 + i;
            float val = fmaxf(acc[ct][i] + bias_i[i], 0.f);
            size_t oi = ((size_t)(b * 256 + gr)) * HWd + gc;
            u16 h = f2bf(val);
            feat_hi[oi] = h;
            feat_lo[oi] = f2bf(val - bf2f(h));
        }
    }
}

// ---------------------------------------------------------------------------
// K2: bf16x3 MFMA GEMM with register prefetch of the next K-tile.
// mode 0: Co fp32.  mode 1: Ch/Cl bf16 hi/lo.
// ---------------------------------------------------------------------------
__global__ __launch_bounds__(256, 4) void gemm_mfma3(
    const u16* __restrict__ Ah, const u16* __restrict__ Al,
    const u16* __restrict__ Bh, const u16* __restrict__ Bl,
    const float* __restrict__ bias,
    float* __restrict__ Co, u16* __restrict__ Ch, u16* __restrict__ Cl,
    int N, int K, int mode) {
    __shared__ u16 sAh[64 * 72], sAl[64 * 72], sBh[64 * 72], sBl[64 * 72];
    int tid = threadIdx.x;
    int w = tid >> 6;
    int L = tid & 63;
    int m16 = L & 15, qd = L >> 4;
    int mb = blockIdx.y * 64, nb = blockIdx.x * 64;

    f32x4 acc[4];
    #pragma unroll
    for (int i = 0; i < 4; i++) acc[i] = (f32x4){0.f, 0.f, 0.f, 0.f};

    int r = tid >> 2, s = tid & 3;
    const u16* pAh = Ah + (size_t)(mb + r) * K + s * 16;
    const u16* pAl = Al + (size_t)(mb + r) * K + s * 16;
    const u16* pBh = Bh + (size_t)(nb + r) * K + s * 16;
    const u16* pBl = Bl + (size_t)(nb + r) * K + s * 16;
    u16* dAh = &sAh[r * 72 + s * 16];
    u16* dAl = &sAl[r * 72 + s * 16];
    u16* dBh = &sBh[r * 72 + s * 16];
    u16* dBl = &sBl[r * 72 + s * 16];

    uint4 a0 = *(const uint4*)(pAh);
    uint4 a1 = *(const uint4*)(pAh + 8);
    uint4 a2 = *(const uint4*)(pAl);
    uint4 a3 = *(const uint4*)(pAl + 8);
    uint4 b0 = *(const uint4*)(pBh);
    uint4 b1 = *(const uint4*)(pBh + 8);
    uint4 b2 = *(const uint4*)(pBl);
    uint4 b3 = *(const uint4*)(pBl + 8);

    for (int k0 = 0; k0 < K; k0 += 64) {
        __syncthreads();
        *(uint4*)(dAh) = a0; *(uint4*)(dAh + 8) = a1;
        *(uint4*)(dAl) = a2; *(uint4*)(dAl + 8) = a3;
        *(uint4*)(dBh) = b0; *(uint4*)(dBh + 8) = b1;
        *(uint4*)(dBl) = b2; *(uint4*)(dBl + 8) = b3;
        __syncthreads();
        int kn = k0 + 64;
        if (kn < K) {   // prefetch next tile; latency hidden under MFMA below
            a0 = *(const uint4*)(pAh + kn);
            a1 = *(const uint4*)(pAh + kn + 8);
            a2 = *(const uint4*)(pAl + kn);
            a3 = *(const uint4*)(pAl + kn + 8);
            b0 = *(const uint4*)(pBh + kn);
            b1 = *(const uint4*)(pBh + kn + 8);
            b2 = *(const uint4*)(pBl + kn);
            b3 = *(const uint4*)(pBl + kn + 8);
        }
        #pragma unroll
        for (int c = 0; c < 2; c++) {
            int ab = (w * 16 + m16) * 72 + c * 32 + qd * 8;
            short8 aH = *(const short8*)&sAh[ab];
            short8 aL = *(const short8*)&sAl[ab];
            #pragma unroll
            for (int ct = 0; ct < 4; ct++) {
                int bb = (ct * 16 + m16) * 72 + c * 32 + qd * 8;
                short8 bH = *(const short8*)&sBh[bb];
                short8 bL = *(const short8*)&sBl[bb];
                acc[ct] = __builtin_amdgcn_mfma_f32_16x16x32_bf16(aH, bH, acc[ct], 0, 0, 0);
                acc[ct] = __builtin_amdgcn_mfma_f32_16x16x32_bf16(aH, bL, acc[ct], 0, 0, 0);
                acc[ct] = __builtin_amdgcn_mfma_f32_16x16x32_bf16(aL, bH, acc[ct], 0, 0, 0);
            }
        }
    }

    #pragma unroll
    for (int ct = 0; ct < 4; ct++) {
        int gc = nb + ct * 16 + m16;
        float bv = bias[gc];
        #pragma unroll
        for (int i = 0; i < 4; i++) {
            int gr = mb + w * 16 + qd * 4 + i;
            float val = acc[ct][i] + bv;
            size_t oi = (size_t)gr * N + gc;
            if (mode == 0) {
                Co[oi] = val;
            } else {
                u16 h = f2bf(val);
                Ch[oi] = h;
                Cl[oi] = f2bf(val - bf2f(h));
            }
        }
    }
}

// ---------------------------------------------------------------------------
// K4: attention over fused qkv[4096][768] (q|k|v per row).
// grid (b, h, qc): 512 blocks.  Thread t: q-row = qc*64 + (t>>2), owns 8 of
// the 32 dims (sub = t&3).  Dot closed by shfl_xor(1),(2).
// ---------------------------------------------------------------------------
__global__ __launch_bounds__(256) void attention(
    const float* __restrict__ qkv, float* __restrict__ o) {
    __shared__ float ksh[64][32];
    __shared__ float vsh[64][32];
    int b = blockIdx.x, h = blockIdx.y, qc = blockIdx.z;
    int t = threadIdx.x;
    int row = t >> 2, sub = t & 3;
    int r = qc * 64 + row;
    const float rs = 0.17677669529663687f;  // 1/sqrt(32)

    float qr[8];
    const float* qrow = qkv + ((size_t)(b * Pd + r)) * 768 + h * DHd + sub * 8;
    #pragma unroll
    for (int d = 0; d < 8; d++) qr[d] = qrow[d];

    float m = -1e30f, l = 0.f;
    float oacc[8];
    #pragma unroll
    for (int d = 0; d < 8; d++) oacc[d] = 0.f;

    for (int ch = 0; ch < 4; ch++) {
        __syncthreads();
        {
            const float* srck = qkv + ((size_t)(b * Pd + ch * 64 + row)) * 768 + 256 + h * DHd + sub * 8;
            const float* srcv = srck + 256;
            float4 k0 = *(const float4*)(srck);
            float4 k1 = *(const float4*)(srck + 4);
            float4 v0 = *(const float4*)(srcv);
            float4 v1 = *(const float4*)(srcv + 4);
            *(float4*)&ksh[row][sub * 8]     = k0;
            *(float4*)&ksh[row][sub * 8 + 4] = k1;
            *(float4*)&vsh[row][sub * 8]     = v0;
            *(float4*)&vsh[row][sub * 8 + 4] = v1;
        }
        __syncthreads();
        #pragma unroll 2
        for (int kk = 0; kk < 64; kk++) {
            float4 ka = *(const float4*)&ksh[kk][sub * 8];
            float4 kb = *(const float4*)&ksh[kk][sub * 8 + 4];
            float s0 = qr[0] * ka.x + qr[1] * ka.y;
            float s1 = qr[2] * ka.z + qr[3] * ka.w;
            float s2 = qr[4] * kb.x + qr[5] * kb.y;
            float s3 = qr[6] * kb.z + qr[7] * kb.w;
            float s = (s0 + s1) + (s2 + s3);
            s += __shfl_xor(s, 1);
            s += __shfl_xor(s, 2);
            s *= rs;
            float mnew = fmaxf(m, s);
            float scale = __expf(m - mnew);
            float pexp = __expf(s - mnew);
            l = l * scale + pexp;
            float4 va = *(const float4*)&vsh[kk][sub * 8];
            float4 vb = *(const float4*)&vsh[kk][sub * 8 + 4];
            oacc[0] = fmaf(oacc[0], scale, pexp * va.x);
            oacc[1] = fmaf(oacc[1], scale, pexp * va.y);
            oacc[2] = fmaf(oacc[2], scale, pexp * va.z);
            oacc[3] = fmaf(oacc[3], scale, pexp * va.w);
            oacc[4] = fmaf(oacc[4], scale, pexp * vb.x);
            oacc[5] = fmaf(oacc[5], scale, pexp * vb.y);
            oacc[6] = fmaf(oacc[6], scale, pexp * vb.z);
            oacc[7] = fmaf(oacc[7], scale, pexp * vb.w);
            m = mnew;
        }
    }
    float rinv = 1.f / l;
    float* orow = o + ((size_t)(b * Pd + r)) * Ed + h * DHd + sub * 8;
    #pragma unroll
    for (int d = 0; d < 8; d++) orow[d] = oacc[d] * rinv;
}

// ---------------------------------------------------------------------------
// K5: fused head. One wave per (b,p): tp = tanh(o@M2 + h0); pos embed; patches.
// ---------------------------------------------------------------------------
#define PATCH_OUT 995328   // 16*256*243
__global__ __launch_bounds__(256) void head_kernel(
    const float* __restrict__ o, const float* __restrict__ M2,
    const float* __restrict__ h0, const float* __restrict__ pos_w,
    const float* __restrict__ pos_b, const float* __restrict__ x,
    float* __restrict__ out) {
    int w = threadIdx.x >> 6, lane = threadIdx.x & 63;
    int bp = blockIdx.x * 4 + w;
    int b = bp >> 8;

    const float* orow = o + (size_t)bp * Ed;
    float4 o4 = *(const float4*)(orow + lane * 4);
    int e0 = lane * 4;
    float s0 = o4.x * M2[2 * e0 + 0] + o4.y * M2[2 * e0 + 2] + o4.z * M2[2 * e0 + 4] + o4.w * M2[2 * e0 + 6];
    float s1 = o4.x * M2[2 * e0 + 1] + o4.y * M2[2 * e0 + 3] + o4.z * M2[2 * e0 + 5] + o4.w * M2[2 * e0 + 7];
    #pragma unroll
    for (int off = 32; off; off >>= 1) { s0 += __shfl_xor(s0, off); s1 += __shfl_xor(s1, off); }

    float tx = tanhf(s0 + h0[0]);
    float ty = tanhf(s1 + h0[1]);

    {
        float pv = tx * pos_w[lane] + ty * pos_w[64 + lane] + pos_b[lane];
        out[PATCH_OUT + bp * POSDd + lane] = pv;
    }

    const float* xb = x + b * 3 * HWd;
    #pragma unroll
    for (int s = 0; s < 4; s++) {
        int idx = s * 64 + lane;
        if (idx < 243) {
            int c = idx / 81;
            int rem = idx - c * 81;
            int iy = rem / 9;
            int jx = rem - iy * 9;
            float basex = (2.f * jx + 1.f) / 9.f - 1.f;
            float basey = (2.f * iy + 1.f) / 9.f - 1.f;
            float gx = 0.140625f * basex + tx;
            float gy = 0.140625f * basey + ty;
            float ix  = ((gx + 1.f) * 64.f - 1.f) * 0.5f;
            float iyf = ((gy + 1.f) * 64.f - 1.f) * 0.5f;
            float x0f = floorf(ix), y0f = floorf(iyf);
            float wx = ix - x0f, wy = iyf - y0f;
            int x0i = min(max((int)x0f, 0), 63);
            int x1i = min(max((int)x0f + 1, 0), 63);
            int y0i = min(max((int)y0f, 0), 63);
            int y1i = min(max((int)y0f + 1, 0), 63);
            const float* xc = xb + c * HWd;
            float v00 = xc[y0i * Wd + x0i];
            float v01 = xc[y0i * Wd + x1i];
            float v10 = xc[y1i * Wd + x0i];
            float v11 = xc[y1i * Wd + x1i];
            float val = v00 * (1.f - wx) * (1.f - wy) + v01 * wx * (1.f - wy)
                      + v10 * (1.f - wx) * wy + v11 * wx * wy;
            out[bp * 243 + idx] = val;
        }
    }
}

// ---------------------------------------------------------------------------
extern "C" void kernel_launch(void* const* d_in, const int* in_sizes, int n_in,
                              void* d_out, int out_size, void* d_ws, size_t ws_size,
                              hipStream_t stream) {
    (void)in_sizes; (void)n_in; (void)out_size;
    const float* x      = (const float*)d_in[0];
    const float* conv_w = (const float*)d_in[1];
    const float* conv_b = (const float*)d_in[2];
    const float* in_w   = (const float*)d_in[3];
    const float* in_b   = (const float*)d_in[4];
    const float* wq     = (const float*)d_in[5];
    const float* bq     = (const float*)d_in[6];
    const float* wk     = (const float*)d_in[7];
    const float* bk     = (const float*)d_in[8];
    const float* wv     = (const float*)d_in[9];
    const float* bv     = (const float*)d_in[10];
    const float* wo     = (const float*)d_in[11];
    const float* bo     = (const float*)d_in[12];
    const float* out_w  = (const float*)d_in[13];
    const float* out_b  = (const float*)d_in[14];
    const float* fc_w   = (const float*)d_in[15];
    const float* fc_b   = (const float*)d_in[16];
    const float* pos_w  = (const float*)d_in[17];
    const float* pos_b  = (const float*)d_in[18];

    // ws budget (u16): feat 2*CB*1M, tok 2*1M, inw_t 2*1M, wqkv_t 2*196608,
    // convw 2*65536.  fp32: bqkv 768, qkv 3M, o 1M, G/M2/h0 ~1K.
    int CB = 16;
    for (;;) {
        size_t need = ((size_t)(2 * CB + 4) * 1048576 + 2 * 196608 + 2 * 65536) * 2
                    + (768 + 3145728 + 1048576 + 2048) * 4;
        if (need <= ws_size || CB == 1) break;
        CB >>= 1;
    }
    int nchunks = 16 / CB;

    char* base = (char*)d_ws;
    u16* feat_hi = (u16*)base;
    u16* feat_lo = feat_hi + (size_t)CB * 1048576;
    u16* tok_hi  = feat_lo + (size_t)CB * 1048576;
    u16* tok_lo  = tok_hi + 1048576;
    u16* inw_h   = tok_lo + 1048576;
    u16* inw_l   = inw_h + 1048576;
    u16* wqkv_h  = inw_l + 1048576;
    u16* wqkv_l  = wqkv_h + 196608;
    u16* convw_h = wqkv_l + 196608;
    u16* convw_l = convw_h + 65536;
    float* bqkv  = (float*)(convw_l + 65536);
    float* qkv   = bqkv + 768;
    float* o     = qkv + 3145728;
    float* G     = o + 1048576;
    float* M2    = G + 512;
    float* h0    = M2 + 512;
    float* out   = (float*)d_out;

    hipLaunchKernelGGL(precompute_G, dim3(258), dim3(64), 0, stream,
                       out_w, fc_w, out_b, fc_b, G, h0);
    hipLaunchKernelGGL(precompute_M2, dim3(258), dim3(64), 0, stream,
                       wo, bo, G, M2, h0);
    hipLaunchKernelGGL(prep_weight_t, dim3(64, 4), dim3(256), 0, stream,
                       in_w, inw_h, inw_l, 4096, 256);
    hipLaunchKernelGGL(prep_weight_t, dim3(4, 4), dim3(256), 0, stream,
                       wq, wqkv_h, wqkv_l, 256, 256);
    hipLaunchKernelGGL(prep_weight_t, dim3(4, 4), dim3(256), 0, stream,
                       wk, wqkv_h + 256 * 256, wqkv_l + 256 * 256, 256, 256);
    hipLaunchKernelGGL(prep_weight_t, dim3(4, 4), dim3(256), 0, stream,
                       wv, wqkv_h + 512 * 256, wqkv_l + 512 * 256, 256, 256);
    hipLaunchKernelGGL(prep_convw, dim3(256), dim3(256), 0, stream,
                       conv_w, convw_h, convw_l);
    hipLaunchKernelGGL(concat_bias, dim3(1), dim3(256), 0, stream,
                       bq, bk, bv, bqkv);

    for (int c = 0; c < nchunks; ++c) {
        hipLaunchKernelGGL(conv_gemm, dim3(64, 4, CB), dim3(256), 0, stream,
                           convw_h, convw_l,
                           x + (size_t)c * CB * 3 * HWd, conv_b,
                           feat_hi, feat_lo);
        hipLaunchKernelGGL(gemm_mfma3, dim3(4, CB * 4), dim3(256), 0, stream,
                           feat_hi, feat_lo, inw_h, inw_l, in_b,
                           (float*)nullptr,
                           tok_hi + (size_t)c * CB * 65536,
                           tok_lo + (size_t)c * CB * 65536,
                           256, 4096, 1);
    }
    // fused q|k|v GEMM: C[4096][768]
    hipLaunchKernelGGL(gemm_mfma3, dim3(12, 64), dim3(256), 0, stream,
                       tok_hi, tok_lo, wqkv_h, wqkv_l, bqkv,
                       qkv, (u16*)nullptr, (u16*)nullptr, 768, 256, 0);
    hipLaunchKernelGGL(attention, dim3(16, 8, 4), dim3(256), 0, stream, qkv, o);
    hipLaunchKernelGGL(head_kernel, dim3(1024), dim3(256), 0, stream,
                       o, M2, h0, pos_w, pos_b, x, out);
}

// Round 9
// 301.951 us; speedup vs baseline: 2.6934x; 1.1145x over previous
//
#include <hip/hip_runtime.h>
#include <hip/hip_bf16.h>

// Problem dims
#define Bd 16
#define Cd 3
#define Hd 64
#define Wd 64
#define Pd 256
#define PSd 9
#define Ed 256
#define NHd 8
#define DHd 32
#define HWd 4096
#define POSDd 64

typedef unsigned short u16;
typedef short short8 __attribute__((ext_vector_type(8)));
typedef float f32x4 __attribute__((ext_vector_type(4)));

__device__ __forceinline__ float bf2f(u16 u) {
    union { unsigned int i; float f; } c; c.i = ((unsigned int)u) << 16; return c.f;
}
__device__ __forceinline__ u16 f2bf(float f) {
    unsigned int x = __float_as_uint(f);
    unsigned int r = (x + 0x7fffu + ((x >> 16) & 1u)) >> 16;
    return (u16)r;
}

// ---------------------------------------------------------------------------
// K0a: G[e][j] = sum_hw out_w[e,hw] * fc_w[hw,j]   (e<256, j<2)
//      blocks 256,257: h0[j] = sum_hw out_b[hw]*fc_w[hw,j] + fc_b[j]
// ---------------------------------------------------------------------------
__global__ __launch_bounds__(64) void precompute_G(
    const float* __restrict__ out_w, const float* __restrict__ fc_w,
    const float* __restrict__ out_b, const float* __restrict__ fc_b,
    float* __restrict__ G, float* __restrict__ h0) {
    int blk = blockIdx.x, lane = threadIdx.x;
    if (blk < 256) {
        int e = blk;
        float a0 = 0.f, a1 = 0.f;
        for (int i = lane; i < HWd; i += 64) {
            float a = out_w[e * HWd + i];
            a0 += a * fc_w[2 * i];
            a1 += a * fc_w[2 * i + 1];
        }
        #pragma unroll
        for (int off = 32; off; off >>= 1) { a0 += __shfl_xor(a0, off); a1 += __shfl_xor(a1, off); }
        if (lane == 0) { G[2 * e] = a0; G[2 * e + 1] = a1; }
    } else {
        int j = blk - 256;
        float a = 0.f;
        for (int i = lane; i < HWd; i += 64) a += out_b[i] * fc_w[2 * i + j];
        #pragma unroll
        for (int off = 32; off; off >>= 1) a += __shfl_xor(a, off);
        if (lane == 0) h0[j] = a + fc_b[j];
    }
}

// ---------------------------------------------------------------------------
// K0b (parallel): block e<256: M2[e][:] = sum_f wo[e,f]*G[f][:]
//                 blocks 256,257: h0[j] += sum_e bo[e]*G[e][j]
// ---------------------------------------------------------------------------
__global__ __launch_bounds__(64) void precompute_M2(
    const float* __restrict__ wo, const float* __restrict__ bo,
    const float* __restrict__ G, float* __restrict__ M2, float* __restrict__ h0) {
    int blk = blockIdx.x, lane = threadIdx.x;
    if (blk < 256) {
        float m0 = 0.f, m1 = 0.f;
        for (int f = lane; f < Ed; f += 64) {
            float wv = wo[blk * Ed + f];
            m0 += wv * G[2 * f];
            m1 += wv * G[2 * f + 1];
        }
        #pragma unroll
        for (int off = 32; off; off >>= 1) { m0 += __shfl_xor(m0, off); m1 += __shfl_xor(m1, off); }
        if (lane == 0) { M2[2 * blk] = m0; M2[2 * blk + 1] = m1; }
    } else {
        int j = blk - 256;
        float hh = 0.f;
        for (int f = lane; f < Ed; f += 64) hh += bo[f] * G[2 * f + j];
        #pragma unroll
        for (int off = 32; off; off >>= 1) hh += __shfl_xor(hh, off);
        if (lane == 0) h0[j] += hh;
    }
}

// ---------------------------------------------------------------------------
// prep: W[K][N] fp32 -> Th/Tl[N][K] bf16 hi/lo, LDS-tiled transpose.
// ---------------------------------------------------------------------------
__global__ __launch_bounds__(256) void prep_weight_t(
    const float* __restrict__ W, u16* __restrict__ Th, u16* __restrict__ Tl,
    int K, int N) {
    __shared__ u16 th[64][65];
    __shared__ u16 tl[64][65];
    int k0 = blockIdx.x * 64, n0 = blockIdx.y * 64;
    int col = threadIdx.x & 63, r4 = threadIdx.x >> 6;
    #pragma unroll
    for (int i = 0; i < 16; i++) {
        int kr = 4 * i + r4;
        float v = W[(size_t)(k0 + kr) * N + n0 + col];
        u16 h = f2bf(v);
        th[col][kr] = h;
        tl[col][kr] = f2bf(v - bf2f(h));
    }
    __syncthreads();
    #pragma unroll
    for (int i = 0; i < 16; i++) {
        int nr = 4 * i + r4;
        Th[(size_t)(n0 + nr) * K + k0 + col] = th[nr][col];
        Tl[(size_t)(n0 + nr) * K + k0 + col] = tl[nr][col];
    }
}

// prep conv weights: conv_w[p][243] fp32 -> Ah/Al[p][256] bf16 hi/lo (K-pad 0)
__global__ __launch_bounds__(256) void prep_convw(
    const float* __restrict__ W, u16* __restrict__ Ah, u16* __restrict__ Al) {
    int p = blockIdx.x, k = threadIdx.x;
    float v = (k < 243) ? W[p * 243 + k] : 0.f;
    u16 h = f2bf(v);
    Ah[p * 256 + k] = h;
    Al[p * 256 + k] = f2bf(v - bf2f(h));
}

// concat bq,bk,bv -> b3[768]
__global__ __launch_bounds__(256) void concat_bias(
    const float* __restrict__ bq, const float* __restrict__ bk,
    const float* __restrict__ bv, float* __restrict__ b3) {
    int t = threadIdx.x;
    b3[t] = bq[t]; b3[256 + t] = bk[t]; b3[512 + t] = bv[t];
}

// ---------------------------------------------------------------------------
// K1 v2: implicit-GEMM conv via MFMA (bf16x3), all 256 output channels per
// block.  B-tile [64 hw][64 k] built in-LDS ONCE per K-iter and consumed by
// all 4 p-tiles (was rebuilt 4x).  A fragments live in registers, loaded
// straight from the L2-resident 256KB prepped weight array.
// grid: (64 hw-rows, CB batches)
// ---------------------------------------------------------------------------
__global__ __launch_bounds__(256, 2) void conv_gemm(
    const u16* __restrict__ Ah, const u16* __restrict__ Al,
    const float* __restrict__ x, const float* __restrict__ conv_b,
    u16* __restrict__ feat_hi, u16* __restrict__ feat_lo) {
    __shared__ u16 sBh[64 * 72], sBl[64 * 72];
    __shared__ float wls[3 * 9 * 72];   // zero-padded 9-row window, 3 channels
    int tid = threadIdx.x;
    int w = tid >> 6, L = tid & 63;
    int m16 = L & 15, qd = L >> 4;
    int y = blockIdx.x;                 // image row == hw-tile
    int nb = y << 6;
    int b = blockIdx.y;

    for (int i = tid; i < 3 * 9 * 72; i += 256) wls[i] = 0.f;
    __syncthreads();
    for (int i = tid; i < 3 * 9 * 64; i += 256) {
        int c = i / 576, rem = i - c * 576, wr = rem >> 6, col = rem & 63;
        int iy = y - 4 + wr;
        if (iy >= 0 && iy < 64)
            wls[c * 648 + wr * 72 + 4 + col] = x[((b * 3 + c) << 12) + (iy << 6) + col];
    }
    __syncthreads();

    f32x4 acc[4][4];                    // [p-tile][ct]
    #pragma unroll
    for (int mt = 0; mt < 4; mt++)
        #pragma unroll
        for (int ct = 0; ct < 4; ct++) acc[mt][ct] = (f32x4){0.f, 0.f, 0.f, 0.f};

    int n = tid >> 2, kb = (tid & 3) << 4;   // B build: hw-col, 16-k strip
    int arow = w * 16 + m16;                 // A row within a 64-p tile

    for (int k0 = 0; k0 < 256; k0 += 64) {
        // A fragments for all 4 p-tiles, this k0 (global, L2-hit)
        short8 afh[4][2], afl[4][2];
        #pragma unroll
        for (int mt = 0; mt < 4; mt++)
            #pragma unroll
            for (int c = 0; c < 2; c++) {
                int ao = (mt * 64 + arow) * 256 + k0 + c * 32 + qd * 8;
                afh[mt][c] = *(const short8*)(Ah + ao);
                afl[mt][c] = *(const short8*)(Al + ao);
            }
        // build this iter's 16-k strip of B in regs (reads wls only)
        u16 hbuf[16] __attribute__((aligned(8)));
        u16 lbuf[16] __attribute__((aligned(8)));
        #pragma unroll
        for (int j = 0; j < 16; j++) {
            int k = k0 + kb + j;
            float v = 0.f;
            if (k < 243) {
                int c = (k >= 81) + (k >= 162);
                int rem = k - c * 81;
                int dy = (rem * 57) >> 9;       // rem/9 for rem<81
                int dx = rem - dy * 9;
                v = wls[c * 648 + dy * 72 + dx + n];
            }
            u16 h = f2bf(v);
            hbuf[j] = h;
            lbuf[j] = f2bf(v - bf2f(h));
        }
        __syncthreads();                    // prior iter's sB reads done
        #pragma unroll
        for (int t = 0; t < 4; t++) {
            *(ushort4*)&sBh[n * 72 + kb + 4 * t] = *(ushort4*)&hbuf[4 * t];
            *(ushort4*)&sBl[n * 72 + kb + 4 * t] = *(ushort4*)&lbuf[4 * t];
        }
        __syncthreads();                    // sB ready
        #pragma unroll
        for (int c = 0; c < 2; c++) {
            #pragma unroll
            for (int ct = 0; ct < 4; ct++) {
                int bb = (ct * 16 + m16) * 72 + c * 32 + qd * 8;
                short8 bH = *(const short8*)&sBh[bb];
                short8 bL = *(const short8*)&sBl[bb];
                #pragma unroll
                for (int mt = 0; mt < 4; mt++) {
                    acc[mt][ct] = __builtin_amdgcn_mfma_f32_16x16x32_bf16(afh[mt][c], bH, acc[mt][ct], 0, 0, 0);
                    acc[mt][ct] = __builtin_amdgcn_mfma_f32_16x16x32_bf16(afh[mt][c], bL, acc[mt][ct], 0, 0, 0);
                    acc[mt][ct] = __builtin_amdgcn_mfma_f32_16x16x32_bf16(afl[mt][c], bH, acc[mt][ct], 0, 0, 0);
                }
            }
        }
    }

    // epilogue: bias + relu + hi/lo split -> feat[(b*256+p)][hw]
    #pragma unroll
    for (int mt = 0; mt < 4; mt++) {
        #pragma unroll
        for (int i = 0; i < 4; i++) {
            int gr = mt * 64 + w * 16 + qd * 4 + i;
            float bv = conv_b[gr];
            #pragma unroll
            for (int ct = 0; ct < 4; ct++) {
                int gc = nb + ct * 16 + m16;
                float val = fmaxf(acc[mt][ct][i] + bv, 0.f);
                size_t oi = ((size_t)(b * 256 + gr)) * HWd + gc;
                u16 h = f2bf(val);
                feat_hi[oi] = h;
                feat_lo[oi] = f2bf(val - bf2f(h));
            }
        }
    }
}

// ---------------------------------------------------------------------------
// K2: bf16x3 MFMA GEMM with register prefetch + optional K-split (blockIdx.z).
// K = row stride of A/B in k-elems; klen = this block's k-range length.
// mode 0: Co[oi] = val + bias.   mode 1: Ch/Cl bf16 hi/lo (+bias).
// mode 2: Co[z*pstride + oi] = val (no bias) — fp32 partial for K-split.
// ---------------------------------------------------------------------------
__global__ __launch_bounds__(256, 4) void gemm_mfma3(
    const u16* __restrict__ Ah, const u16* __restrict__ Al,
    const u16* __restrict__ Bh, const u16* __restrict__ Bl,
    const float* __restrict__ bias,
    float* __restrict__ Co, u16* __restrict__ Ch, u16* __restrict__ Cl,
    int N, int K, int klen, long long pstride, int mode) {
    __shared__ u16 sAh[64 * 72], sAl[64 * 72], sBh[64 * 72], sBl[64 * 72];
    int tid = threadIdx.x;
    int w = tid >> 6;
    int L = tid & 63;
    int m16 = L & 15, qd = L >> 4;
    int mb = blockIdx.y * 64, nb = blockIdx.x * 64;
    int kbeg = blockIdx.z * klen;

    f32x4 acc[4];
    #pragma unroll
    for (int i = 0; i < 4; i++) acc[i] = (f32x4){0.f, 0.f, 0.f, 0.f};

    int r = tid >> 2, s = tid & 3;
    const u16* pAh = Ah + (size_t)(mb + r) * K + kbeg + s * 16;
    const u16* pAl = Al + (size_t)(mb + r) * K + kbeg + s * 16;
    const u16* pBh = Bh + (size_t)(nb + r) * K + kbeg + s * 16;
    const u16* pBl = Bl + (size_t)(nb + r) * K + kbeg + s * 16;
    u16* dAh = &sAh[r * 72 + s * 16];
    u16* dAl = &sAl[r * 72 + s * 16];
    u16* dBh = &sBh[r * 72 + s * 16];
    u16* dBl = &sBl[r * 72 + s * 16];

    uint4 a0 = *(const uint4*)(pAh);
    uint4 a1 = *(const uint4*)(pAh + 8);
    uint4 a2 = *(const uint4*)(pAl);
    uint4 a3 = *(const uint4*)(pAl + 8);
    uint4 b0 = *(const uint4*)(pBh);
    uint4 b1 = *(const uint4*)(pBh + 8);
    uint4 b2 = *(const uint4*)(pBl);
    uint4 b3 = *(const uint4*)(pBl + 8);

    for (int k0 = 0; k0 < klen; k0 += 64) {
        __syncthreads();
        *(uint4*)(dAh) = a0; *(uint4*)(dAh + 8) = a1;
        *(uint4*)(dAl) = a2; *(uint4*)(dAl + 8) = a3;
        *(uint4*)(dBh) = b0; *(uint4*)(dBh + 8) = b1;
        *(uint4*)(dBl) = b2; *(uint4*)(dBl + 8) = b3;
        __syncthreads();
        int kn = k0 + 64;
        if (kn < klen) {   // prefetch next tile; latency hidden under MFMA
            a0 = *(const uint4*)(pAh + kn);
            a1 = *(const uint4*)(pAh + kn + 8);
            a2 = *(const uint4*)(pAl + kn);
            a3 = *(const uint4*)(pAl + kn + 8);
            b0 = *(const uint4*)(pBh + kn);
            b1 = *(const uint4*)(pBh + kn + 8);
            b2 = *(const uint4*)(pBl + kn);
            b3 = *(const uint4*)(pBl + kn + 8);
        }
        #pragma unroll
        for (int c = 0; c < 2; c++) {
            int ab = (w * 16 + m16) * 72 + c * 32 + qd * 8;
            short8 aH = *(const short8*)&sAh[ab];
            short8 aL = *(const short8*)&sAl[ab];
            #pragma unroll
            for (int ct = 0; ct < 4; ct++) {
                int bb = (ct * 16 + m16) * 72 + c * 32 + qd * 8;
                short8 bH = *(const short8*)&sBh[bb];
                short8 bL = *(const short8*)&sBl[bb];
                acc[ct] = __builtin_amdgcn_mfma_f32_16x16x32_bf16(aH, bH, acc[ct], 0, 0, 0);
                acc[ct] = __builtin_amdgcn_mfma_f32_16x16x32_bf16(aH, bL, acc[ct], 0, 0, 0);
                acc[ct] = __builtin_amdgcn_mfma_f32_16x16x32_bf16(aL, bH, acc[ct], 0, 0, 0);
            }
        }
    }

    #pragma unroll
    for (int ct = 0; ct < 4; ct++) {
        int gc = nb + ct * 16 + m16;
        float bv = (mode == 2) ? 0.f : bias[gc];
        #pragma unroll
        for (int i = 0; i < 4; i++) {
            int gr = mb + w * 16 + qd * 4 + i;
            float val = acc[ct][i] + bv;
            size_t oi = (size_t)gr * N + gc;
            if (mode == 0) {
                Co[oi] = val;
            } else if (mode == 2) {
                Co[(size_t)blockIdx.z * pstride + oi] = val;
            } else {
                u16 h = f2bf(val);
                Ch[oi] = h;
                Cl[oi] = f2bf(val - bf2f(h));
            }
        }
    }
}

// ---------------------------------------------------------------------------
// K3: reduce 4 K-split partials + bias, emit bf16 hi/lo.  N=256 fixed.
// ---------------------------------------------------------------------------
__global__ __launch_bounds__(256) void reduce_split(
    const float* __restrict__ part, const float* __restrict__ bias,
    u16* __restrict__ Ch, u16* __restrict__ Cl, int total) {
    int i = (blockIdx.x * 256 + threadIdx.x) * 4;
    if (i >= total) return;
    float4 s0 = *(const float4*)(part + i);
    float4 s1 = *(const float4*)(part + (size_t)total + i);
    float4 s2 = *(const float4*)(part + 2 * (size_t)total + i);
    float4 s3 = *(const float4*)(part + 3 * (size_t)total + i);
    float4 bv = *(const float4*)(bias + (i & 255));
    float v[4] = { s0.x + s1.x + s2.x + s3.x + bv.x,
                   s0.y + s1.y + s2.y + s3.y + bv.y,
                   s0.z + s1.z + s2.z + s3.z + bv.z,
                   s0.w + s1.w + s2.w + s3.w + bv.w };
    u16 hb[4] __attribute__((aligned(8)));
    u16 lb[4] __attribute__((aligned(8)));
    #pragma unroll
    for (int j = 0; j < 4; j++) {
        u16 h = f2bf(v[j]);
        hb[j] = h;
        lb[j] = f2bf(v[j] - bf2f(h));
    }
    *(ushort4*)(Ch + i) = *(ushort4*)hb;
    *(ushort4*)(Cl + i) = *(ushort4*)lb;
}

// ---------------------------------------------------------------------------
// K4: attention over fused qkv[4096][768] (q|k|v per row).
// grid (b, h, qc): 512 blocks.  Thread t: q-row = qc*64 + (t>>2), owns 8 of
// the 32 dims (sub = t&3).  Dot closed by shfl_xor(1),(2).
// ---------------------------------------------------------------------------
__global__ __launch_bounds__(256) void attention(
    const float* __restrict__ qkv, float* __restrict__ o) {
    __shared__ float ksh[64][32];
    __shared__ float vsh[64][32];
    int b = blockIdx.x, h = blockIdx.y, qc = blockIdx.z;
    int t = threadIdx.x;
    int row = t >> 2, sub = t & 3;
    int r = qc * 64 + row;
    const float rs = 0.17677669529663687f;  // 1/sqrt(32)

    float qr[8];
    const float* qrow = qkv + ((size_t)(b * Pd + r)) * 768 + h * DHd + sub * 8;
    #pragma unroll
    for (int d = 0; d < 8; d++) qr[d] = qrow[d];

    float m = -1e30f, l = 0.f;
    float oacc[8];
    #pragma unroll
    for (int d = 0; d < 8; d++) oacc[d] = 0.f;

    for (int ch = 0; ch < 4; ch++) {
        __syncthreads();
        {
            const float* srck = qkv + ((size_t)(b * Pd + ch * 64 + row)) * 768 + 256 + h * DHd + sub * 8;
            const float* srcv = srck + 256;
            float4 k0 = *(const float4*)(srck);
            float4 k1 = *(const float4*)(srck + 4);
            float4 v0 = *(const float4*)(srcv);
            float4 v1 = *(const float4*)(srcv + 4);
            *(float4*)&ksh[row][sub * 8]     = k0;
            *(float4*)&ksh[row][sub * 8 + 4] = k1;
            *(float4*)&vsh[row][sub * 8]     = v0;
            *(float4*)&vsh[row][sub * 8 + 4] = v1;
        }
        __syncthreads();
        #pragma unroll 2
        for (int kk = 0; kk < 64; kk++) {
            float4 ka = *(const float4*)&ksh[kk][sub * 8];
            float4 kb = *(const float4*)&ksh[kk][sub * 8 + 4];
            float s0 = qr[0] * ka.x + qr[1] * ka.y;
            float s1 = qr[2] * ka.z + qr[3] * ka.w;
            float s2 = qr[4] * kb.x + qr[5] * kb.y;
            float s3 = qr[6] * kb.z + qr[7] * kb.w;
            float s = (s0 + s1) + (s2 + s3);
            s += __shfl_xor(s, 1);
            s += __shfl_xor(s, 2);
            s *= rs;
            float mnew = fmaxf(m, s);
            float scale = __expf(m - mnew);
            float pexp = __expf(s - mnew);
            l = l * scale + pexp;
            float4 va = *(const float4*)&vsh[kk][sub * 8];
            float4 vb = *(const float4*)&vsh[kk][sub * 8 + 4];
            oacc[0] = fmaf(oacc[0], scale, pexp * va.x);
            oacc[1] = fmaf(oacc[1], scale, pexp * va.y);
            oacc[2] = fmaf(oacc[2], scale, pexp * va.z);
            oacc[3] = fmaf(oacc[3], scale, pexp * va.w);
            oacc[4] = fmaf(oacc[4], scale, pexp * vb.x);
            oacc[5] = fmaf(oacc[5], scale, pexp * vb.y);
            oacc[6] = fmaf(oacc[6], scale, pexp * vb.z);
            oacc[7] = fmaf(oacc[7], scale, pexp * vb.w);
            m = mnew;
        }
    }
    float rinv = 1.f / l;
    float* orow = o + ((size_t)(b * Pd + r)) * Ed + h * DHd + sub * 8;
    #pragma unroll
    for (int d = 0; d < 8; d++) orow[d] = oacc[d] * rinv;
}

// ---------------------------------------------------------------------------
// K5: fused head. One wave per (b,p): tp = tanh(o@M2 + h0); pos embed; patches.
// ---------------------------------------------------------------------------
#define PATCH_OUT 995328   // 16*256*243
__global__ __launch_bounds__(256) void head_kernel(
    const float* __restrict__ o, const float* __restrict__ M2,
    const float* __restrict__ h0, const float* __restrict__ pos_w,
    const float* __restrict__ pos_b, const float* __restrict__ x,
    float* __restrict__ out) {
    int w = threadIdx.x >> 6, lane = threadIdx.x & 63;
    int bp = blockIdx.x * 4 + w;
    int b = bp >> 8;

    const float* orow = o + (size_t)bp * Ed;
    float4 o4 = *(const float4*)(orow + lane * 4);
    int e0 = lane * 4;
    float s0 = o4.x * M2[2 * e0 + 0] + o4.y * M2[2 * e0 + 2] + o4.z * M2[2 * e0 + 4] + o4.w * M2[2 * e0 + 6];
    float s1 = o4.x * M2[2 * e0 + 1] + o4.y * M2[2 * e0 + 3] + o4.z * M2[2 * e0 + 5] + o4.w * M2[2 * e0 + 7];
    #pragma unroll
    for (int off = 32; off; off >>= 1) { s0 += __shfl_xor(s0, off); s1 += __shfl_xor(s1, off); }

    float tx = tanhf(s0 + h0[0]);
    float ty = tanhf(s1 + h0[1]);

    {
        float pv = tx * pos_w[lane] + ty * pos_w[64 + lane] + pos_b[lane];
        out[PATCH_OUT + bp * POSDd + lane] = pv;
    }

    const float* xb = x + b * 3 * HWd;
    #pragma unroll
    for (int s = 0; s < 4; s++) {
        int idx = s * 64 + lane;
        if (idx < 243) {
            int c = idx / 81;
            int rem = idx - c * 81;
            int iy = rem / 9;
            int jx = rem - iy * 9;
            float basex = (2.f * jx + 1.f) / 9.f - 1.f;
            float basey = (2.f * iy + 1.f) / 9.f - 1.f;
            float gx = 0.140625f * basex + tx;
            float gy = 0.140625f * basey + ty;
            float ix  = ((gx + 1.f) * 64.f - 1.f) * 0.5f;
            float iyf = ((gy + 1.f) * 64.f - 1.f) * 0.5f;
            float x0f = floorf(ix), y0f = floorf(iyf);
            float wx = ix - x0f, wy = iyf - y0f;
            int x0i = min(max((int)x0f, 0), 63);
            int x1i = min(max((int)x0f + 1, 0), 63);
            int y0i = min(max((int)y0f, 0), 63);
            int y1i = min(max((int)y0f + 1, 0), 63);
            const float* xc = xb + c * HWd;
            float v00 = xc[y0i * Wd + x0i];
            float v01 = xc[y0i * Wd + x1i];
            float v10 = xc[y1i * Wd + x0i];
            float v11 = xc[y1i * Wd + x1i];
            float val = v00 * (1.f - wx) * (1.f - wy) + v01 * wx * (1.f - wy)
                      + v10 * (1.f - wx) * wy + v11 * wx * wy;
            out[bp * 243 + idx] = val;
        }
    }
}

// ---------------------------------------------------------------------------
extern "C" void kernel_launch(void* const* d_in, const int* in_sizes, int n_in,
                              void* d_out, int out_size, void* d_ws, size_t ws_size,
                              hipStream_t stream) {
    (void)in_sizes; (void)n_in; (void)out_size;
    const float* x      = (const float*)d_in[0];
    const float* conv_w = (const float*)d_in[1];
    const float* conv_b = (const float*)d_in[2];
    const float* in_w   = (const float*)d_in[3];
    const float* in_b   = (const float*)d_in[4];
    const float* wq     = (const float*)d_in[5];
    const float* bq     = (const float*)d_in[6];
    const float* wk     = (const float*)d_in[7];
    const float* bk     = (const float*)d_in[8];
    const float* wv     = (const float*)d_in[9];
    const float* bv     = (const float*)d_in[10];
    const float* wo     = (const float*)d_in[11];
    const float* bo     = (const float*)d_in[12];
    const float* out_w  = (const float*)d_in[13];
    const float* out_b  = (const float*)d_in[14];
    const float* fc_w   = (const float*)d_in[15];
    const float* fc_b   = (const float*)d_in[16];
    const float* pos_w  = (const float*)d_in[17];
    const float* pos_b  = (const float*)d_in[18];

    // ws budget (u16): feat 2*CB*1M, tok 2*1M, inw_t 2*1M, wqkv_t 2*196608,
    // convw 2*65536.  fp32: bqkv 768, qkv 3M, o 1M, partials 4*CB*65536, misc.
    int CB = 16;
    for (;;) {
        size_t need = ((size_t)(2 * CB + 4) * 1048576 + 2 * 196608 + 2 * 65536) * 2
                    + (768 + 3145728 + 1048576 + 4ull * CB * 65536 + 2048) * 4;
        if (need <= ws_size || CB == 1) break;
        CB >>= 1;
    }
    int nchunks = 16 / CB;

    char* base = (char*)d_ws;
    u16* feat_hi = (u16*)base;
    u16* feat_lo = feat_hi + (size_t)CB * 1048576;
    u16* tok_hi  = feat_lo + (size_t)CB * 1048576;
    u16* tok_lo  = tok_hi + 1048576;
    u16* inw_h   = tok_lo + 1048576;
    u16* inw_l   = inw_h + 1048576;
    u16* wqkv_h  = inw_l + 1048576;
    u16* wqkv_l  = wqkv_h + 196608;
    u16* convw_h = wqkv_l + 196608;
    u16* convw_l = convw_h + 65536;
    float* bqkv  = (float*)(convw_l + 65536);
    float* qkv   = bqkv + 768;
    float* o     = qkv + 3145728;
    float* part  = o + 1048576;                    // 4*CB*65536 floats
    float* G     = part + 4ull * CB * 65536;
    float* M2    = G + 512;
    float* h0    = M2 + 512;
    float* out   = (float*)d_out;

    hipLaunchKernelGGL(precompute_G, dim3(258), dim3(64), 0, stream,
                       out_w, fc_w, out_b, fc_b, G, h0);
    hipLaunchKernelGGL(precompute_M2, dim3(258), dim3(64), 0, stream,
                       wo, bo, G, M2, h0);
    hipLaunchKernelGGL(prep_weight_t, dim3(64, 4), dim3(256), 0, stream,
                       in_w, inw_h, inw_l, 4096, 256);
    hipLaunchKernelGGL(prep_weight_t, dim3(4, 4), dim3(256), 0, stream,
                       wq, wqkv_h, wqkv_l, 256, 256);
    hipLaunchKernelGGL(prep_weight_t, dim3(4, 4), dim3(256), 0, stream,
                       wk, wqkv_h + 256 * 256, wqkv_l + 256 * 256, 256, 256);
    hipLaunchKernelGGL(prep_weight_t, dim3(4, 4), dim3(256), 0, stream,
                       wv, wqkv_h + 512 * 256, wqkv_l + 512 * 256, 256, 256);
    hipLaunchKernelGGL(prep_convw, dim3(256), dim3(256), 0, stream,
                       conv_w, convw_h, convw_l);
    hipLaunchKernelGGL(concat_bias, dim3(1), dim3(256), 0, stream,
                       bq, bk, bv, bqkv);

    for (int c = 0; c < nchunks; ++c) {
        hipLaunchKernelGGL(conv_gemm, dim3(64, CB), dim3(256), 0, stream,
                           convw_h, convw_l,
                           x + (size_t)c * CB * 3 * HWd, conv_b,
                           feat_hi, feat_lo);
        // tok GEMM, K-split 4 -> fp32 partials
        hipLaunchKernelGGL(gemm_mfma3, dim3(4, CB * 4, 4), dim3(256), 0, stream,
                           feat_hi, feat_lo, inw_h, inw_l, in_b,
                           part, (u16*)nullptr, (u16*)nullptr,
                           256, 4096, 1024, (long long)CB * 65536, 2);
        hipLaunchKernelGGL(reduce_split, dim3(CB * 65536 / 1024), dim3(256), 0, stream,
                           part, in_b,
                           tok_hi + (size_t)c * CB * 65536,
                           tok_lo + (size_t)c * CB * 65536,
                           CB * 65536);
    }
    // fused q|k|v GEMM: C[4096][768]
    hipLaunchKernelGGL(gemm_mfma3, dim3(12, 64, 1), dim3(256), 0, stream,
                       tok_hi, tok_lo, wqkv_h, wqkv_l, bqkv,
                       qkv, (u16*)nullptr, (u16*)nullptr, 768, 256, 256, 0LL, 0);
    hipLaunchKernelGGL(attention, dim3(16, 8, 4), dim3(256), 0, stream, qkv, o);
    hipLaunchKernelGGL(head_kernel, dim3(1024), dim3(256), 0, stream,
                       o, M2, h0, pos_w, pos_b, x, out);
}

// Round 11
// 270.672 us; speedup vs baseline: 3.0047x; 1.1156x over previous
//
#include <hip/hip_runtime.h>
#include <hip/hip_bf16.h>

// Problem dims
#define Bd 16
#define Cd 3
#define Hd 64
#define Wd 64
#define Pd 256
#define PSd 9
#define Ed 256
#define NHd 8
#define DHd 32
#define HWd 4096
#define POSDd 64

typedef unsigned short u16;
typedef short short8 __attribute__((ext_vector_type(8)));
typedef float f32x4 __attribute__((ext_vector_type(4)));

__device__ __forceinline__ float bf2f(u16 u) {
    union { unsigned int i; float f; } c; c.i = ((unsigned int)u) << 16; return c.f;
}
__device__ __forceinline__ u16 f2bf(float f) {
    unsigned int x = __float_as_uint(f);
    unsigned int r = (x + 0x7fffu + ((x >> 16) & 1u)) >> 16;
    return (u16)r;
}

// ---------------------------------------------------------------------------
// K0a: G[e][j] = sum_hw out_w[e,hw] * fc_w[hw,j]
// ---------------------------------------------------------------------------
__global__ __launch_bounds__(64) void precompute_G(
    const float* __restrict__ out_w, const float* __restrict__ fc_w,
    const float* __restrict__ out_b, const float* __restrict__ fc_b,
    float* __restrict__ G, float* __restrict__ h0) {
    int blk = blockIdx.x, lane = threadIdx.x;
    if (blk < 256) {
        int e = blk;
        float a0 = 0.f, a1 = 0.f;
        for (int i = lane; i < HWd; i += 64) {
            float a = out_w[e * HWd + i];
            a0 += a * fc_w[2 * i];
            a1 += a * fc_w[2 * i + 1];
        }
        #pragma unroll
        for (int off = 32; off; off >>= 1) { a0 += __shfl_xor(a0, off); a1 += __shfl_xor(a1, off); }
        if (lane == 0) { G[2 * e] = a0; G[2 * e + 1] = a1; }
    } else {
        int j = blk - 256;
        float a = 0.f;
        for (int i = lane; i < HWd; i += 64) a += out_b[i] * fc_w[2 * i + j];
        #pragma unroll
        for (int off = 32; off; off >>= 1) a += __shfl_xor(a, off);
        if (lane == 0) h0[j] = a + fc_b[j];
    }
}

// ---------------------------------------------------------------------------
// K0b: M2[e][:] = sum_f wo[e,f]*G[f][:];  h0[j] += sum_e bo[e]*G[e][j]
// ---------------------------------------------------------------------------
__global__ __launch_bounds__(64) void precompute_M2(
    const float* __restrict__ wo, const float* __restrict__ bo,
    const float* __restrict__ G, float* __restrict__ M2, float* __restrict__ h0) {
    int blk = blockIdx.x, lane = threadIdx.x;
    if (blk < 256) {
        float m0 = 0.f, m1 = 0.f;
        for (int f = lane; f < Ed; f += 64) {
            float wv = wo[blk * Ed + f];
            m0 += wv * G[2 * f];
            m1 += wv * G[2 * f + 1];
        }
        #pragma unroll
        for (int off = 32; off; off >>= 1) { m0 += __shfl_xor(m0, off); m1 += __shfl_xor(m1, off); }
        if (lane == 0) { M2[2 * blk] = m0; M2[2 * blk + 1] = m1; }
    } else {
        int j = blk - 256;
        float hh = 0.f;
        for (int f = lane; f < Ed; f += 64) hh += bo[f] * G[2 * f + j];
        #pragma unroll
        for (int off = 32; off; off >>= 1) hh += __shfl_xor(hh, off);
        if (lane == 0) h0[j] += hh;
    }
}

// ---------------------------------------------------------------------------
// prep: W[K][N] fp32 -> Th/Tl[N][K] bf16 hi/lo, LDS-tiled transpose.
// ---------------------------------------------------------------------------
__global__ __launch_bounds__(256) void prep_weight_t(
    const float* __restrict__ W, u16* __restrict__ Th, u16* __restrict__ Tl,
    int K, int N) {
    __shared__ u16 th[64][65];
    __shared__ u16 tl[64][65];
    int k0 = blockIdx.x * 64, n0 = blockIdx.y * 64;
    int col = threadIdx.x & 63, r4 = threadIdx.x >> 6;
    #pragma unroll
    for (int i = 0; i < 16; i++) {
        int kr = 4 * i + r4;
        float v = W[(size_t)(k0 + kr) * N + n0 + col];
        u16 h = f2bf(v);
        th[col][kr] = h;
        tl[col][kr] = f2bf(v - bf2f(h));
    }
    __syncthreads();
    #pragma unroll
    for (int i = 0; i < 16; i++) {
        int nr = 4 * i + r4;
        Th[(size_t)(n0 + nr) * K + k0 + col] = th[nr][col];
        Tl[(size_t)(n0 + nr) * K + k0 + col] = tl[nr][col];
    }
}

// prep conv weights: conv_w[p][243] fp32 -> Ah/Al[p][256] bf16 hi/lo (K-pad 0)
__global__ __launch_bounds__(256) void prep_convw(
    const float* __restrict__ W, u16* __restrict__ Ah, u16* __restrict__ Al) {
    int p = blockIdx.x, k = threadIdx.x;
    float v = (k < 243) ? W[p * 243 + k] : 0.f;
    u16 h = f2bf(v);
    Ah[p * 256 + k] = h;
    Al[p * 256 + k] = f2bf(v - bf2f(h));
}

// concat bq,bk,bv -> b3[768]
__global__ __launch_bounds__(256) void concat_bias(
    const float* __restrict__ bq, const float* __restrict__ bk,
    const float* __restrict__ bv, float* __restrict__ b3) {
    int t = threadIdx.x;
    b3[t] = bq[t]; b3[256 + t] = bk[t]; b3[512 + t] = bv[t];
}

// ---------------------------------------------------------------------------
// K1 v2: implicit-GEMM conv via MFMA (bf16x3), all 256 output channels/block.
// ---------------------------------------------------------------------------
__global__ __launch_bounds__(256, 2) void conv_gemm(
    const u16* __restrict__ Ah, const u16* __restrict__ Al,
    const float* __restrict__ x, const float* __restrict__ conv_b,
    u16* __restrict__ feat_hi, u16* __restrict__ feat_lo) {
    __shared__ u16 sBh[64 * 72], sBl[64 * 72];
    __shared__ float wls[3 * 9 * 72];
    int tid = threadIdx.x;
    int w = tid >> 6, L = tid & 63;
    int m16 = L & 15, qd = L >> 4;
    int y = blockIdx.x;
    int nb = y << 6;
    int b = blockIdx.y;

    for (int i = tid; i < 3 * 9 * 72; i += 256) wls[i] = 0.f;
    __syncthreads();
    for (int i = tid; i < 3 * 9 * 64; i += 256) {
        int c = i / 576, rem = i - c * 576, wr = rem >> 6, col = rem & 63;
        int iy = y - 4 + wr;
        if (iy >= 0 && iy < 64)
            wls[c * 648 + wr * 72 + 4 + col] = x[((b * 3 + c) << 12) + (iy << 6) + col];
    }
    __syncthreads();

    f32x4 acc[4][4];
    #pragma unroll
    for (int mt = 0; mt < 4; mt++)
        #pragma unroll
        for (int ct = 0; ct < 4; ct++) acc[mt][ct] = (f32x4){0.f, 0.f, 0.f, 0.f};

    int n = tid >> 2, kb = (tid & 3) << 4;
    int arow = w * 16 + m16;

    for (int k0 = 0; k0 < 256; k0 += 64) {
        short8 afh[4][2], afl[4][2];
        #pragma unroll
        for (int mt = 0; mt < 4; mt++)
            #pragma unroll
            for (int c = 0; c < 2; c++) {
                int ao = (mt * 64 + arow) * 256 + k0 + c * 32 + qd * 8;
                afh[mt][c] = *(const short8*)(Ah + ao);
                afl[mt][c] = *(const short8*)(Al + ao);
            }
        u16 hbuf[16] __attribute__((aligned(8)));
        u16 lbuf[16] __attribute__((aligned(8)));
        #pragma unroll
        for (int j = 0; j < 16; j++) {
            int k = k0 + kb + j;
            float v = 0.f;
            if (k < 243) {
                int c = (k >= 81) + (k >= 162);
                int rem = k - c * 81;
                int dy = (rem * 57) >> 9;
                int dx = rem - dy * 9;
                v = wls[c * 648 + dy * 72 + dx + n];
            }
            u16 h = f2bf(v);
            hbuf[j] = h;
            lbuf[j] = f2bf(v - bf2f(h));
        }
        __syncthreads();
        #pragma unroll
        for (int t = 0; t < 4; t++) {
            *(ushort4*)&sBh[n * 72 + kb + 4 * t] = *(ushort4*)&hbuf[4 * t];
            *(ushort4*)&sBl[n * 72 + kb + 4 * t] = *(ushort4*)&lbuf[4 * t];
        }
        __syncthreads();
        #pragma unroll
        for (int c = 0; c < 2; c++) {
            #pragma unroll
            for (int ct = 0; ct < 4; ct++) {
                int bb = (ct * 16 + m16) * 72 + c * 32 + qd * 8;
                short8 bH = *(const short8*)&sBh[bb];
                short8 bL = *(const short8*)&sBl[bb];
                #pragma unroll
                for (int mt = 0; mt < 4; mt++) {
                    acc[mt][ct] = __builtin_amdgcn_mfma_f32_16x16x32_bf16(afh[mt][c], bH, acc[mt][ct], 0, 0, 0);
                    acc[mt][ct] = __builtin_amdgcn_mfma_f32_16x16x32_bf16(afh[mt][c], bL, acc[mt][ct], 0, 0, 0);
                    acc[mt][ct] = __builtin_amdgcn_mfma_f32_16x16x32_bf16(afl[mt][c], bH, acc[mt][ct], 0, 0, 0);
                }
            }
        }
    }

    #pragma unroll
    for (int mt = 0; mt < 4; mt++) {
        #pragma unroll
        for (int i = 0; i < 4; i++) {
            int gr = mt * 64 + w * 16 + qd * 4 + i;
            float bv = conv_b[gr];
            #pragma unroll
            for (int ct = 0; ct < 4; ct++) {
                int gc = nb + ct * 16 + m16;
                float val = fmaxf(acc[mt][ct][i] + bv, 0.f);
                size_t oi = ((size_t)(b * 256 + gr)) * HWd + gc;
                u16 h = f2bf(val);
                feat_hi[oi] = h;
                feat_lo[oi] = f2bf(val - bf2f(h));
            }
        }
    }
}

// ---------------------------------------------------------------------------
// K2: bf16x3 MFMA GEMM with register prefetch + optional K-split (blockIdx.z).
// mode 0: Co = val + bias.  mode 1: Ch/Cl bf16 hi/lo (+bias).
// mode 2: Co[z*pstride + oi] = val (no bias) — fp32 partial for K-split.
// ---------------------------------------------------------------------------
__global__ __launch_bounds__(256, 4) void gemm_mfma3(
    const u16* __restrict__ Ah, const u16* __restrict__ Al,
    const u16* __restrict__ Bh, const u16* __restrict__ Bl,
    const float* __restrict__ bias,
    float* __restrict__ Co, u16* __restrict__ Ch, u16* __restrict__ Cl,
    int N, int K, int klen, long long pstride, int mode) {
    __shared__ u16 sAh[64 * 72], sAl[64 * 72], sBh[64 * 72], sBl[64 * 72];
    int tid = threadIdx.x;
    int w = tid >> 6;
    int L = tid & 63;
    int m16 = L & 15, qd = L >> 4;
    int mb = blockIdx.y * 64, nb = blockIdx.x * 64;
    int kbeg = blockIdx.z * klen;

    f32x4 acc[4];
    #pragma unroll
    for (int i = 0; i < 4; i++) acc[i] = (f32x4){0.f, 0.f, 0.f, 0.f};

    int r = tid >> 2, s = tid & 3;
    const u16* pAh = Ah + (size_t)(mb + r) * K + kbeg + s * 16;
    const u16* pAl = Al + (size_t)(mb + r) * K + kbeg + s * 16;
    const u16* pBh = Bh + (size_t)(nb + r) * K + kbeg + s * 16;
    const u16* pBl = Bl + (size_t)(nb + r) * K + kbeg + s * 16;
    u16* dAh = &sAh[r * 72 + s * 16];
    u16* dAl = &sAl[r * 72 + s * 16];
    u16* dBh = &sBh[r * 72 + s * 16];
    u16* dBl = &sBl[r * 72 + s * 16];

    uint4 a0 = *(const uint4*)(pAh);
    uint4 a1 = *(const uint4*)(pAh + 8);
    uint4 a2 = *(const uint4*)(pAl);
    uint4 a3 = *(const uint4*)(pAl + 8);
    uint4 b0 = *(const uint4*)(pBh);
    uint4 b1 = *(const uint4*)(pBh + 8);
    uint4 b2 = *(const uint4*)(pBl);
    uint4 b3 = *(const uint4*)(pBl + 8);

    for (int k0 = 0; k0 < klen; k0 += 64) {
        __syncthreads();
        *(uint4*)(dAh) = a0; *(uint4*)(dAh + 8) = a1;
        *(uint4*)(dAl) = a2; *(uint4*)(dAl + 8) = a3;
        *(uint4*)(dBh) = b0; *(uint4*)(dBh + 8) = b1;
        *(uint4*)(dBl) = b2; *(uint4*)(dBl + 8) = b3;
        __syncthreads();
        int kn = k0 + 64;
        if (kn < klen) {
            a0 = *(const uint4*)(pAh + kn);
            a1 = *(const uint4*)(pAh + kn + 8);
            a2 = *(const uint4*)(pAl + kn);
            a3 = *(const uint4*)(pAl + kn + 8);
            b0 = *(const uint4*)(pBh + kn);
            b1 = *(const uint4*)(pBh + kn + 8);
            b2 = *(const uint4*)(pBl + kn);
            b3 = *(const uint4*)(pBl + kn + 8);
        }
        #pragma unroll
        for (int c = 0; c < 2; c++) {
            int ab = (w * 16 + m16) * 72 + c * 32 + qd * 8;
            short8 aH = *(const short8*)&sAh[ab];
            short8 aL = *(const short8*)&sAl[ab];
            #pragma unroll
            for (int ct = 0; ct < 4; ct++) {
                int bb = (ct * 16 + m16) * 72 + c * 32 + qd * 8;
                short8 bH = *(const short8*)&sBh[bb];
                short8 bL = *(const short8*)&sBl[bb];
                acc[ct] = __builtin_amdgcn_mfma_f32_16x16x32_bf16(aH, bH, acc[ct], 0, 0, 0);
                acc[ct] = __builtin_amdgcn_mfma_f32_16x16x32_bf16(aH, bL, acc[ct], 0, 0, 0);
                acc[ct] = __builtin_amdgcn_mfma_f32_16x16x32_bf16(aL, bH, acc[ct], 0, 0, 0);
            }
        }
    }

    #pragma unroll
    for (int ct = 0; ct < 4; ct++) {
        int gc = nb + ct * 16 + m16;
        float bv = (mode == 2) ? 0.f : bias[gc];
        #pragma unroll
        for (int i = 0; i < 4; i++) {
            int gr = mb + w * 16 + qd * 4 + i;
            float val = acc[ct][i] + bv;
            size_t oi = (size_t)gr * N + gc;
            if (mode == 0) {
                Co[oi] = val;
            } else if (mode == 2) {
                Co[(size_t)blockIdx.z * pstride + oi] = val;
            } else {
                u16 h = f2bf(val);
                Ch[oi] = h;
                Cl[oi] = f2bf(val - bf2f(h));
            }
        }
    }
}

// ---------------------------------------------------------------------------
// K3: reduce 4 K-split partials + bias, emit bf16 hi/lo.  N=256 fixed.
// ---------------------------------------------------------------------------
__global__ __launch_bounds__(256) void reduce_split(
    const float* __restrict__ part, const float* __restrict__ bias,
    u16* __restrict__ Ch, u16* __restrict__ Cl, int total) {
    int i = (blockIdx.x * 256 + threadIdx.x) * 4;
    if (i >= total) return;
    float4 s0 = *(const float4*)(part + i);
    float4 s1 = *(const float4*)(part + (size_t)total + i);
    float4 s2 = *(const float4*)(part + 2 * (size_t)total + i);
    float4 s3 = *(const float4*)(part + 3 * (size_t)total + i);
    float4 bv = *(const float4*)(bias + (i & 255));
    float v[4] = { s0.x + s1.x + s2.x + s3.x + bv.x,
                   s0.y + s1.y + s2.y + s3.y + bv.y,
                   s0.z + s1.z + s2.z + s3.z + bv.z,
                   s0.w + s1.w + s2.w + s3.w + bv.w };
    u16 hb[4] __attribute__((aligned(8)));
    u16 lb[4] __attribute__((aligned(8)));
    #pragma unroll
    for (int j = 0; j < 4; j++) {
        u16 h = f2bf(v[j]);
        hb[j] = h;
        lb[j] = f2bf(v[j] - bf2f(h));
    }
    *(ushort4*)(Ch + i) = *(ushort4*)hb;
    *(ushort4*)(Cl + i) = *(ushort4*)lb;
}

// ---------------------------------------------------------------------------
// K4a: transpose V: qkv_h/l cols 512..767 -> vT[b][h][d][k] bf16 hi/lo.
// grid (16,8): per (b,h), LDS-tiled: coalesced global both sides.
// NOTE: uint4 = 8 u16 — each thread owns a 32-elem k-segment => FOUR copies.
// (Round-10 bug: only 2 copies at stride 16 left half of vT poisoned.)
// ---------------------------------------------------------------------------
__global__ __launch_bounds__(256) void transpose_v(
    const u16* __restrict__ qkvh, const u16* __restrict__ qkvl,
    u16* __restrict__ vTh, u16* __restrict__ vTl) {
    __shared__ u16 th[32][264];
    __shared__ u16 tl[32][264];
    int b = blockIdx.x, h = blockIdx.y;
    int t = threadIdx.x;
    {
        const u16* srch = qkvh + ((size_t)(b * 256 + t)) * 768 + 512 + h * 32;
        const u16* srcl = qkvl + ((size_t)(b * 256 + t)) * 768 + 512 + h * 32;
        #pragma unroll
        for (int j = 0; j < 4; j++) {
            short8 vh = *(const short8*)(srch + j * 8);
            short8 vl = *(const short8*)(srcl + j * 8);
            #pragma unroll
            for (int e = 0; e < 8; e++) {
                th[j * 8 + e][t] = (u16)vh[e];
                tl[j * 8 + e][t] = (u16)vl[e];
            }
        }
    }
    __syncthreads();
    {
        int d = t >> 3, seg = t & 7;
        size_t dst = ((size_t)((b * 8 + h) * 32 + d)) * 256 + seg * 32;
        #pragma unroll
        for (int j = 0; j < 4; j++) {
            *(uint4*)(vTh + dst + j * 8) = *(uint4*)&th[d][seg * 32 + j * 8];
            *(uint4*)(vTl + dst + j * 8) = *(uint4*)&tl[d][seg * 32 + j * 8];
        }
    }
}

// ---------------------------------------------------------------------------
// K4b: MFMA attention.  grid (b, h, qc=4), 256 thr = 4 waves x 16 q-rows.
// QK^T: bf16x3 on q/k hi/lo read DIRECT from global (L2-hot).  Raw-exp
// softmax (|s| small, no max needed); per-row l via shfl within quad-group.
// P->bf16 via per-wave LDS slice (within-wave round-trip, NO barrier).
// PV: P.(Vh+Vl), V^T frags direct from global.
// ---------------------------------------------------------------------------
__global__ __launch_bounds__(256) void attention_mfma(
    const u16* __restrict__ qkvh, const u16* __restrict__ qkvl,
    const u16* __restrict__ vTh, const u16* __restrict__ vTl,
    float* __restrict__ o) {
    __shared__ u16 ph[4][16][264];
    int b = blockIdx.x, h = blockIdx.y, qc = blockIdx.z;
    int tid = threadIdx.x;
    int w = tid >> 6, L = tid & 63;
    int m16 = L & 15, qd = L >> 4;
    const float rs = 0.17677669529663687f;  // 1/sqrt(32)

    // Q fragments (A: m=lane&15, k=qd*8+j)
    size_t qoff = ((size_t)(b * 256 + qc * 64 + w * 16 + m16)) * 768 + h * 32 + qd * 8;
    short8 qH = *(const short8*)(qkvh + qoff);
    short8 qL = *(const short8*)(qkvl + qoff);

    // S = Q K^T  (bf16x3)
    f32x4 sacc[16];
    #pragma unroll
    for (int nt = 0; nt < 16; nt++) {
        size_t koff = ((size_t)(b * 256 + nt * 16 + m16)) * 768 + 256 + h * 32 + qd * 8;
        short8 bH = *(const short8*)(qkvh + koff);
        short8 bL = *(const short8*)(qkvl + koff);
        f32x4 a = (f32x4){0.f, 0.f, 0.f, 0.f};
        a = __builtin_amdgcn_mfma_f32_16x16x32_bf16(qH, bH, a, 0, 0, 0);
        a = __builtin_amdgcn_mfma_f32_16x16x32_bf16(qH, bL, a, 0, 0, 0);
        a = __builtin_amdgcn_mfma_f32_16x16x32_bf16(qL, bH, a, 0, 0, 0);
        sacc[nt] = a;
    }

    // raw-exp softmax; l per C-row (row = qd*4+i)
    float l4[4] = {0.f, 0.f, 0.f, 0.f};
    #pragma unroll
    for (int nt = 0; nt < 16; nt++)
        #pragma unroll
        for (int i = 0; i < 4; i++) {
            float p = __expf(sacc[nt][i] * rs);
            sacc[nt][i] = p;
            l4[i] += p;
        }
    #pragma unroll
    for (int i = 0; i < 4; i++) {
        l4[i] += __shfl_xor(l4[i], 1);
        l4[i] += __shfl_xor(l4[i], 2);
        l4[i] += __shfl_xor(l4[i], 4);
        l4[i] += __shfl_xor(l4[i], 8);
    }

    // P (bf16) to per-wave LDS slice: [q-row local][k-col]
    #pragma unroll
    for (int nt = 0; nt < 16; nt++)
        #pragma unroll
        for (int i = 0; i < 4; i++)
            ph[w][qd * 4 + i][nt * 16 + m16] = f2bf(sacc[nt][i]);

    // O = P V   (A from ph, B = V^T frags from global)
    f32x4 oacc[2];
    oacc[0] = (f32x4){0.f, 0.f, 0.f, 0.f};
    oacc[1] = (f32x4){0.f, 0.f, 0.f, 0.f};
    size_t vbase = ((size_t)(b * 8 + h)) * 32 * 256;
    #pragma unroll
    for (int kt = 0; kt < 8; kt++) {
        short8 pa = *(const short8*)&ph[w][m16][kt * 32 + qd * 8];
        #pragma unroll
        for (int ct = 0; ct < 2; ct++) {
            size_t voff = vbase + (size_t)(ct * 16 + m16) * 256 + kt * 32 + qd * 8;
            short8 vH = *(const short8*)(vTh + voff);
            short8 vL = *(const short8*)(vTl + voff);
            oacc[ct] = __builtin_amdgcn_mfma_f32_16x16x32_bf16(pa, vH, oacc[ct], 0, 0, 0);
            oacc[ct] = __builtin_amdgcn_mfma_f32_16x16x32_bf16(pa, vL, oacc[ct], 0, 0, 0);
        }
    }

    // epilogue: C-layout row = qd*4+i matches l4 ownership
    #pragma unroll
    for (int i = 0; i < 4; i++) {
        float rinv = 1.f / l4[i];
        int orow = b * 256 + qc * 64 + w * 16 + qd * 4 + i;
        #pragma unroll
        for (int ct = 0; ct < 2; ct++)
            o[(size_t)orow * 256 + h * 32 + ct * 16 + m16] = oacc[ct][i] * rinv;
    }
}

// ---------------------------------------------------------------------------
// K5: fused head. One wave per (b,p): tp = tanh(o@M2 + h0); pos embed; patches.
// ---------------------------------------------------------------------------
#define PATCH_OUT 995328   // 16*256*243
__global__ __launch_bounds__(256) void head_kernel(
    const float* __restrict__ o, const float* __restrict__ M2,
    const float* __restrict__ h0, const float* __restrict__ pos_w,
    const float* __restrict__ pos_b, const float* __restrict__ x,
    float* __restrict__ out) {
    int w = threadIdx.x >> 6, lane = threadIdx.x & 63;
    int bp = blockIdx.x * 4 + w;
    int b = bp >> 8;

    const float* orow = o + (size_t)bp * Ed;
    float4 o4 = *(const float4*)(orow + lane * 4);
    int e0 = lane * 4;
    float s0 = o4.x * M2[2 * e0 + 0] + o4.y * M2[2 * e0 + 2] + o4.z * M2[2 * e0 + 4] + o4.w * M2[2 * e0 + 6];
    float s1 = o4.x * M2[2 * e0 + 1] + o4.y * M2[2 * e0 + 3] + o4.z * M2[2 * e0 + 5] + o4.w * M2[2 * e0 + 7];
    #pragma unroll
    for (int off = 32; off; off >>= 1) { s0 += __shfl_xor(s0, off); s1 += __shfl_xor(s1, off); }

    float tx = tanhf(s0 + h0[0]);
    float ty = tanhf(s1 + h0[1]);

    {
        float pv = tx * pos_w[lane] + ty * pos_w[64 + lane] + pos_b[lane];
        out[PATCH_OUT + bp * POSDd + lane] = pv;
    }

    const float* xb = x + b * 3 * HWd;
    #pragma unroll
    for (int s = 0; s < 4; s++) {
        int idx = s * 64 + lane;
        if (idx < 243) {
            int c = idx / 81;
            int rem = idx - c * 81;
            int iy = rem / 9;
            int jx = rem - iy * 9;
            float basex = (2.f * jx + 1.f) / 9.f - 1.f;
            float basey = (2.f * iy + 1.f) / 9.f - 1.f;
            float gx = 0.140625f * basex + tx;
            float gy = 0.140625f * basey + ty;
            float ix  = ((gx + 1.f) * 64.f - 1.f) * 0.5f;
            float iyf = ((gy + 1.f) * 64.f - 1.f) * 0.5f;
            float x0f = floorf(ix), y0f = floorf(iyf);
            float wx = ix - x0f, wy = iyf - y0f;
            int x0i = min(max((int)x0f, 0), 63);
            int x1i = min(max((int)x0f + 1, 0), 63);
            int y0i = min(max((int)y0f, 0), 63);
            int y1i = min(max((int)y0f + 1, 0), 63);
            const float* xc = xb + c * HWd;
            float v00 = xc[y0i * Wd + x0i];
            float v01 = xc[y0i * Wd + x1i];
            float v10 = xc[y1i * Wd + x0i];
            float v11 = xc[y1i * Wd + x1i];
            float val = v00 * (1.f - wx) * (1.f - wy) + v01 * wx * (1.f - wy)
                      + v10 * (1.f - wx) * wy + v11 * wx * wy;
            out[bp * 243 + idx] = val;
        }
    }
}

// ---------------------------------------------------------------------------
extern "C" void kernel_launch(void* const* d_in, const int* in_sizes, int n_in,
                              void* d_out, int out_size, void* d_ws, size_t ws_size,
                              hipStream_t stream) {
    (void)in_sizes; (void)n_in; (void)out_size;
    const float* x      = (const float*)d_in[0];
    const float* conv_w = (const float*)d_in[1];
    const float* conv_b = (const float*)d_in[2];
    const float* in_w   = (const float*)d_in[3];
    const float* in_b   = (const float*)d_in[4];
    const float* wq     = (const float*)d_in[5];
    const float* bq     = (const float*)d_in[6];
    const float* wk     = (const float*)d_in[7];
    const float* bk     = (const float*)d_in[8];
    const float* wv     = (const float*)d_in[9];
    const float* bv     = (const float*)d_in[10];
    const float* wo     = (const float*)d_in[11];
    const float* bo     = (const float*)d_in[12];
    const float* out_w  = (const float*)d_in[13];
    const float* out_b  = (const float*)d_in[14];
    const float* fc_w   = (const float*)d_in[15];
    const float* fc_b   = (const float*)d_in[16];
    const float* pos_w  = (const float*)d_in[17];
    const float* pos_b  = (const float*)d_in[18];

    // ws sizing
    int CB = 16;
    for (;;) {
        size_t u16e = (size_t)(2 * CB + 4) * 1048576 + 2 * 196608 + 2 * 65536
                    + 2 * 3145728 + 2 * 1048576;
        size_t f32e = 768 + 1048576 + 4ull * CB * 65536 + 2048;
        if (u16e * 2 + f32e * 4 <= ws_size || CB == 1) break;
        CB >>= 1;
    }
    int nchunks = 16 / CB;

    char* base = (char*)d_ws;
    u16* feat_hi = (u16*)base;
    u16* feat_lo = feat_hi + (size_t)CB * 1048576;
    u16* tok_hi  = feat_lo + (size_t)CB * 1048576;
    u16* tok_lo  = tok_hi + 1048576;
    u16* inw_h   = tok_lo + 1048576;
    u16* inw_l   = inw_h + 1048576;
    u16* wqkv_h  = inw_l + 1048576;
    u16* wqkv_l  = wqkv_h + 196608;
    u16* convw_h = wqkv_l + 196608;
    u16* convw_l = convw_h + 65536;
    u16* qkvh    = convw_l + 65536;       // 3145728
    u16* qkvl    = qkvh + 3145728;
    u16* vTh     = qkvl + 3145728;        // 1048576
    u16* vTl     = vTh + 1048576;
    float* bqkv  = (float*)(vTl + 1048576);
    float* o     = bqkv + 768;
    float* part  = o + 1048576;           // 4*CB*65536 floats
    float* G     = part + 4ull * CB * 65536;
    float* M2    = G + 512;
    float* h0    = M2 + 512;
    float* out   = (float*)d_out;

    hipLaunchKernelGGL(precompute_G, dim3(258), dim3(64), 0, stream,
                       out_w, fc_w, out_b, fc_b, G, h0);
    hipLaunchKernelGGL(precompute_M2, dim3(258), dim3(64), 0, stream,
                       wo, bo, G, M2, h0);
    hipLaunchKernelGGL(prep_weight_t, dim3(64, 4), dim3(256), 0, stream,
                       in_w, inw_h, inw_l, 4096, 256);
    hipLaunchKernelGGL(prep_weight_t, dim3(4, 4), dim3(256), 0, stream,
                       wq, wqkv_h, wqkv_l, 256, 256);
    hipLaunchKernelGGL(prep_weight_t, dim3(4, 4), dim3(256), 0, stream,
                       wk, wqkv_h + 256 * 256, wqkv_l + 256 * 256, 256, 256);
    hipLaunchKernelGGL(prep_weight_t, dim3(4, 4), dim3(256), 0, stream,
                       wv, wqkv_h + 512 * 256, wqkv_l + 512 * 256, 256, 256);
    hipLaunchKernelGGL(prep_convw, dim3(256), dim3(256), 0, stream,
                       conv_w, convw_h, convw_l);
    hipLaunchKernelGGL(concat_bias, dim3(1), dim3(256), 0, stream,
                       bq, bk, bv, bqkv);

    for (int c = 0; c < nchunks; ++c) {
        hipLaunchKernelGGL(conv_gemm, dim3(64, CB), dim3(256), 0, stream,
                           convw_h, convw_l,
                           x + (size_t)c * CB * 3 * HWd, conv_b,
                           feat_hi, feat_lo);
        hipLaunchKernelGGL(gemm_mfma3, dim3(4, CB * 4, 4), dim3(256), 0, stream,
                           feat_hi, feat_lo, inw_h, inw_l, in_b,
                           part, (u16*)nullptr, (u16*)nullptr,
                           256, 4096, 1024, (long long)CB * 65536, 2);
        hipLaunchKernelGGL(reduce_split, dim3(CB * 65536 / 1024), dim3(256), 0, stream,
                           part, in_b,
                           tok_hi + (size_t)c * CB * 65536,
                           tok_lo + (size_t)c * CB * 65536,
                           CB * 65536);
    }
    // fused q|k|v GEMM -> bf16 hi/lo qkv
    hipLaunchKernelGGL(gemm_mfma3, dim3(12, 64, 1), dim3(256), 0, stream,
                       tok_hi, tok_lo, wqkv_h, wqkv_l, bqkv,
                       (float*)nullptr, qkvh, qkvl, 768, 256, 256, 0LL, 1);
    hipLaunchKernelGGL(transpose_v, dim3(16, 8), dim3(256), 0, stream,
                       qkvh, qkvl, vTh, vTl);
    hipLaunchKernelGGL(attention_mfma, dim3(16, 8, 4), dim3(256), 0, stream,
                       qkvh, qkvl, vTh, vTl, o);
    hipLaunchKernelGGL(head_kernel, dim3(1024), dim3(256), 0, stream,
                       o, M2, h0, pos_w, pos_b, x, out);
}